// Round 14
// baseline (355.760 us; speedup 1.0000x reference)
//
#include <hip/hip_runtime.h>
#include <hip/hip_bf16.h>
#include <float.h>

#define B_ 2
#define N_ 8192
#define C_ 128
#define K_ 16
#define G_ 8
#define NK_ (N_*K_)     // 131072
#define BN_ (B_*N_)     // 16384
#define BNK_ (B_*NK_)   // 262144
#define CN_ (C_*N_)
#define NEG 0.1f
#define EPSV 1e-5f

// KNN grid: 24^3 cells, h=0.5, box [-6,6]
#define GR_ 24
#define NC_ (GR_*GR_*GR_)    // 13824 cells per batch
#define GLOF -6.0f
#define GHF 0.5f
#define KNN_MARGIN 2e-4f
#define EMPTY_KEY 0x7FEFFFFFFFFFFFFFull

typedef __attribute__((ext_vector_type(4))) float f32x4;
typedef __attribute__((ext_vector_type(8))) short s16x8;
typedef __attribute__((ext_vector_type(4))) short s16x4;

__device__ __forceinline__ float leakyf(float x){ return x >= 0.f ? x : NEG*x; }
__device__ __forceinline__ short f2b(float x){
  union { __hip_bfloat16 b; short s; } u; u.b = __float2bfloat16(x); return u.s;
}
__device__ __forceinline__ float b2f(short s){
  union { __hip_bfloat16 b; short s; } u; u.s = s; return __bfloat162float(u.b);
}

// row_shr:1 within 16-lane rows (list lives in lanes 0..15 -> row-local)
__device__ __forceinline__ int dpp_shr1_i(int x){
  return __builtin_amdgcn_update_dpp(x, x, 0x111, 0xF, 0xF, false);
}
__device__ __forceinline__ unsigned long long dpp_shr1_u64(unsigned long long x){
  union { unsigned long long q; int i[2]; } u; u.q = x;
  u.i[0] = dpp_shr1_i(u.i[0]);
  u.i[1] = dpp_shr1_i(u.i[1]);
  return u.q;
}
__device__ __forceinline__ unsigned long long readlane_u64(unsigned long long x, int l){
  union { unsigned long long q; int i[2]; } u; u.q = x;
  union { unsigned long long q; int i[2]; } r;
  r.i[0] = __builtin_amdgcn_readlane(u.i[0], l);
  r.i[1] = __builtin_amdgcn_readlane(u.i[1], l);
  return r.q;
}
// sort key: d2 (clamped >=0) bits, low 13 mantissa bits replaced by idx.
__device__ __forceinline__ unsigned long long d2key(double d2, int idx){
  d2 = fmax(d2, 0.0);
  union { double d; unsigned long long q; } u; u.d = d2;
  return (u.q & ~0x1FFFull) | (unsigned long long)idx;
}
__device__ __forceinline__ double key_upper_d2(unsigned long long k){
  union { unsigned long long q; double d; } u; u.q = k | 0x1FFFull;   // round up: conservative
  return u.d;
}
__device__ __forceinline__ int cell1(float x){
  int c = (int)floorf((x - GLOF)*(1.0f/GHF));
  return min(max(c, 0), GR_-1);
}

// DPP float move (ctrl as template constant; all rows/banks, bound_ctrl=1)
template<int CTRL>
__device__ __forceinline__ float dppf(float x){
  union { float f; int i; } u; u.f = x;
  u.i = __builtin_amdgcn_update_dpp(0, u.i, CTRL, 0xF, 0xF, true);
  return u.f;
}
// 16-lane row sum, identical pairing to xor1/2/4/8 butterfly (bit-identical result)
__device__ __forceinline__ float red16(float x){
  x += dppf<0xB1>(x);    // quad_perm [1,0,3,2] : xor 1
  x += dppf<0x4E>(x);    // quad_perm [2,3,0,1] : xor 2
  x += dppf<0x141>(x);   // row_half_mirror     : xor 4
  x += dppf<0x140>(x);   // row_mirror          : xor 8
  return x;
}

// ---------------- pack xyz -> float4 (w=|p|^2 fp32) + feat -> bf16 PM + cell histogram ----------------
__global__ __launch_bounds__(256) void pack_featb_kernel(const float* __restrict__ xyz,
    const float* __restrict__ feat, float4* __restrict__ pt4, ushort* __restrict__ fb,
    int* __restrict__ cellCnt){
  int e = blockIdx.x*256 + threadIdx.x;
  int b = e >> 13, n = e & (N_-1);
  const float* xb = xyz + b*3*N_;
  float x = xb[n], y = xb[N_+n], z = xb[2*N_+n];
  pt4[e] = make_float4(x, y, z, x*x + y*y + z*z);
  atomicAdd(&cellCnt[b*NC_ + (cell1(z)*GR_ + cell1(y))*GR_ + cell1(x)], 1);
  const float* xin = feat + b*CN_ + n;
  #pragma unroll
  for (int c0 = 0; c0 < C_; c0 += 8){
    s16x8 o8;
    #pragma unroll
    for (int i = 0; i < 8; i++) o8[i] = f2b(xin[(size_t)(c0+i)*N_]);
    *(s16x8*)(fb + (size_t)e*C_ + c0) = o8;
  }
}

// ---------------- exclusive prefix scan over 2*NC_ = 27648 cells (single block, 27/thread) ----------------
__global__ __launch_bounds__(1024) void scan_kernel(const int* __restrict__ cnt,
    int* __restrict__ cellStart, int* __restrict__ cellCur){
  __shared__ int bs[1024];
  int t = threadIdx.x;
  int base = t*27;
  int s = 0;
  for (int i = 0; i < 27; i++) s += cnt[base+i];
  bs[t] = s;
  __syncthreads();
  for (int off = 1; off < 1024; off <<= 1){
    int v = (t >= off) ? bs[t-off] : 0;
    __syncthreads();
    bs[t] += v;
    __syncthreads();
  }
  int run = (t == 0) ? 0 : bs[t-1];
  for (int i = 0; i < 27; i++){
    cellStart[base+i] = run;
    cellCur[base+i]  = run;
    run += cnt[base+i];
  }
  if (t == 1023) cellStart[2*NC_] = BN_;
}

// ---------------- scatter points into cell-sorted order ----------------
__global__ __launch_bounds__(256) void scatter_kernel(const float4* __restrict__ pt4,
    int* __restrict__ cellCur, float4* __restrict__ spts, int* __restrict__ sidx){
  int e = blockIdx.x*256 + threadIdx.x;
  int b = e >> 13;
  float4 p = pt4[e];
  int cid = b*NC_ + (cell1(p.z)*GR_ + cell1(p.y))*GR_ + cell1(p.x);
  int slot = atomicAdd(&cellCur[cid], 1);
  spts[slot] = p;
  sidx[slot] = e & (N_-1);
}

// ---------------- KNN: ring-1 pass -> graded cube expansion (reset+rescan, exact) -> brute fallback ----------------
__global__ __launch_bounds__(512) void knn_kernel(const float4* __restrict__ pt4,
    const float4* __restrict__ spts, const int* __restrict__ sidx,
    const int* __restrict__ cellStart, int* __restrict__ idxo){
  int lane = threadIdx.x & 63, wid = threadIdx.x >> 6;
  int qg = blockIdx.x*8 + wid;           // sorted slot
  int b = qg >> 13;
  float4 qp = spts[qg];
  int nq = sidx[qg];                     // original point index within batch
  double qx = qp.x, qy = qp.y, qz = qp.z;
  double qsq = qx*qx + qy*qy + qz*qz;
  float qx2 = -2.f*qp.x, qy2 = -2.f*qp.y, qz2 = -2.f*qp.z;
  unsigned long long mykey = EMPTY_KEY;  // lanes 0..15: sorted top-16 keys
  float cmpv = FLT_MAX;
  int ci = cell1(qp.x), cj = cell1(qp.y), ck = cell1(qp.z);
  int cbase = b*NC_;

  auto process = [&](unsigned long long m, unsigned long long keyv){
    while (m){
      int src = __ffsll(m) - 1; m &= m - 1;
      unsigned long long kn = readlane_u64(keyv, src);
      bool less = kn < mykey;
      unsigned long long bm = __ballot(less) & 0xFFFFull;
      if (bm){
        int pos = __ffsll(bm) - 1;
        unsigned long long pk = dpp_shr1_u64(mykey);
        if (lane < 16){
          if (lane > pos) mykey = pk;
          else if (lane == pos) mykey = kn;
        }
      }
    }
  };

  auto do_range = [&](int cid0, int cid1){
    int s = cellStart[cid0], e = cellStart[cid1+1];
    for (int off = s; off < e; off += 64){
      int t = off + lane;
      bool valid = t < e;
      float4 pp = make_float4(0.f, 0.f, 0.f, 3.0e38f);
      int oi = 0;
      if (valid){ pp = spts[t]; oi = sidx[t]; }
      float f = fmaf(pp.x, qx2, fmaf(pp.y, qy2, fmaf(pp.z, qz2, pp.w)));
      unsigned long long m = __ballot(valid && (f < cmpv));
      if (m){
        double px = pp.x, py = pp.y, pz = pp.z;
        double psq = px*px + py*py + pz*pz;
        double dot = qx*px + qy*py + qz*pz;
        process(m, d2key(qsq + psq - 2.0*dot, oi));
        cmpv = fminf(cmpv, (float)(key_upper_d2(readlane_u64(mykey, 15)) - qsq) + KNN_MARGIN);
      }
    }
  };

  // full (2r+1)^3 cube, row-merged; RESET list (cube superset of prior scans -> exact, no dups),
  // keep cmpv as a conservative filter
  auto do_cube = [&](int r){
    mykey = EMPTY_KEY;
    int x0 = max(ci-r, 0), x1 = min(ci+r, GR_-1);
    int y0 = max(cj-r, 0), y1 = min(cj+r, GR_-1);
    int z0 = max(ck-r, 0), z1 = min(ck+r, GR_-1);
    for (int z = z0; z <= z1; z++)
      for (int y = y0; y <= y1; y++)
        do_range(cbase + (z*GR_ + y)*GR_ + x0, cbase + (z*GR_ + y)*GR_ + x1);
  };

  // phase 1: ring 0+1 as 9 contiguous x-runs; own row first for fast threshold convergence
  {
    int x0 = max(ci-1, 0), x1 = min(ci+1, GR_-1);
    do_range(cbase + (ck*GR_ + cj)*GR_ + x0, cbase + (ck*GR_ + cj)*GR_ + x1);
    for (int dz = -1; dz <= 1; dz++){
      int z = ck + dz; if (z < 0 || z >= GR_) continue;
      for (int dy = -1; dy <= 1; dy++){
        int y = cj + dy; if (y < 0 || y >= GR_) continue;
        if ((dy | dz) == 0) continue;
        do_range(cbase + (z*GR_ + y)*GR_ + x0, cbase + (z*GR_ + y)*GR_ + x1);
      }
    }
  }

  const double h2 = (double)GHF*(double)GHF;
  double thr_up = key_upper_d2(readlane_u64(mykey, 15));
  if (thr_up > h2*0.999){
    do_cube(2);
    thr_up = key_upper_d2(readlane_u64(mykey, 15));
    if (thr_up > 4.0*h2*0.999){
      do_cube(3);
      thr_up = key_upper_d2(readlane_u64(mykey, 15));
      if (thr_up > 9.0*h2*0.999){
        // final fallback: brute-force over original order; reset list, keep filter
        mykey = EMPTY_KEY;
        const float4* pts = pt4 + (b << 13);
        for (int t0 = 0; t0 < N_; t0 += 64){
          float4 pp = pts[t0 + lane];
          float f = fmaf(pp.x, qx2, fmaf(pp.y, qy2, fmaf(pp.z, qz2, pp.w)));
          unsigned long long m = __ballot(f < cmpv);
          if (m){
            double px = pp.x, py = pp.y, pz = pp.z;
            double psq = px*px + py*py + pz*pz;
            double dot = qx*px + qy*py + qz*pz;
            process(m, d2key(qsq + psq - 2.0*dot, t0 + lane));
            cmpv = fminf(cmpv, (float)(key_upper_d2(readlane_u64(mykey, 15)) - qsq) + KNN_MARGIN);
          }
        }
      }
    }
  }
  if (lane < 16) idxo[((size_t)(b<<13) + nq)*K_ + lane] = (int)(mykey & 0x1FFFull);
}

// ---------------- setup: fused weights (3 x 128^3) + fused biases ----------------
__global__ __launch_bounds__(256) void setup_kernel(const float* __restrict__ W_att1,
    const float* __restrict__ W_pos2, const float* __restrict__ W_q, const float* __restrict__ W_k,
    const float* __restrict__ b_pos2, const float* __restrict__ b_att1,
    const float* __restrict__ b_q, const float* __restrict__ b_k,
    float* __restrict__ Wf, float* __restrict__ Wqa, float* __restrict__ Wka,
    float* __restrict__ bG1, float* __restrict__ bqa, float* __restrict__ bka){
  int bx = blockIdx.x;
  if (bx < 192){
    int which = bx >> 6;
    const float* Bm = which==0 ? W_pos2 : (which==1 ? W_q : W_k);
    float* Cm = which==0 ? Wf : (which==1 ? Wqa : Wka);
    int e = (bx & 63)*256 + threadIdx.x;
    int o = e >> 7, c = e & 127;
    float s = 0.f;
    #pragma unroll 8
    for (int m = 0; m < 128; m++) s += W_att1[o*128+m]*Bm[m*128+c];
    Cm[e] = s;
  } else {
    for (int t = threadIdx.x; t < 384; t += 256){
      int which = t >> 7, o = t & 127;
      const float* v = which==0 ? b_pos2 : (which==1 ? b_q : b_k);
      float* out = which==0 ? bG1 : (which==1 ? bqa : bka);
      float s = which==0 ? b_att1[o] : 0.f;
      for (int m = 0; m < 128; m++) s += W_att1[o*128+m]*v[m];
      out[o] = s;
    }
  }
}

// ---------------- pos_pre group stats (raw conv1 output) ----------------
__global__ __launch_bounds__(256) void pos_stats_kernel(const float4* __restrict__ pt4,
    const int* __restrict__ idx, const float* __restrict__ W1, const float* __restrict__ b1,
    float* __restrict__ gsum, float* __restrict__ gssq){
  __shared__ float ls[G_], lss[G_];
  if (threadIdx.x < G_){ ls[threadIdx.x] = 0.f; lss[threadIdx.x] = 0.f; }
  __syncthreads();
  int p = blockIdx.x*256 + threadIdx.x;
  int b = p >> 17;
  int n = p >> 4;             // global n
  int j = idx[p];
  float4 pj = pt4[(b<<13) + j], pn = pt4[n];
  float rx = pj.x - pn.x, ry = pj.y - pn.y, rz = pj.z - pn.z;
  #pragma unroll
  for (int g = 0; g < G_; g++){
    float s = 0.f, ss = 0.f;
    #pragma unroll
    for (int ci = 0; ci < 16; ci++){
      int c = g*16 + ci;
      float v = b1[c] + W1[3*c]*rx + W1[3*c+1]*ry + W1[3*c+2]*rz;
      s += v; ss += v*v;
    }
    #pragma unroll
    for (int mk = 32; mk; mk >>= 1){ s += __shfl_xor(s, mk, 64); ss += __shfl_xor(ss, mk, 64); }
    if ((threadIdx.x & 63) == 0){ atomicAdd(&ls[g], s); atomicAdd(&lss[g], ss); }
  }
  __syncthreads();
  if (threadIdx.x < G_){
    atomicAdd(&gsum[b*G_ + threadIdx.x], ls[threadIdx.x]);
    atomicAdd(&gssq[b*G_ + threadIdx.x], lss[threadIdx.x]);
  }
}

// ---------------- pos finalize + folded GN params (interleaved float4: sx,sy,sz,so) ----------------
__global__ void posfin_kernel(const float* __restrict__ gsum, const float* __restrict__ gssq,
    const float* __restrict__ W1, const float* __restrict__ b1,
    const float* __restrict__ g1, const float* __restrict__ be1, float* __restrict__ prm, float invcnt){
  __shared__ float sm[16], sr[16];
  int i = threadIdx.x;
  if (i < 16){
    float m = gsum[i]*invcnt;
    float v = gssq[i]*invcnt - m*m;
    v = fmaxf(v, 0.f);
    sm[i] = m; sr[i] = rsqrtf(v + EPSV);
  }
  __syncthreads();
  int b = i >> 7, c = i & 127, g = c >> 4;
  float rs = sr[b*G_+g]*g1[c];
  float4* p4 = (float4*)prm;
  p4[b*128 + c] = make_float4(W1[3*c]*rs, W1[3*c+1]*rs, W1[3*c+2]*rs,
                              (b1[c]-sm[b*G_+g])*rs + be1[c]);
}

// ---------------- att finalize + folded scale/shift (interleaved float2: sc,sh) ----------------
__global__ void attfin_kernel(const float* __restrict__ gsum, const float* __restrict__ gssq,
    const float* __restrict__ ga, const float* __restrict__ bea, float* __restrict__ prm, float invcnt){
  __shared__ float sm[16], sr[16];
  int i = threadIdx.x;
  if (i < 16){
    float m = gsum[i]*invcnt;
    float v = gssq[i]*invcnt - m*m;
    v = fmaxf(v, 0.f);
    sm[i] = m; sr[i] = rsqrtf(v + EPSV);
  }
  __syncthreads();
  int b = i >> 7, c = i & 127, g = c >> 4;
  float sc = ga[c]*sr[b*G_+g];
  float2* p2 = (float2*)prm;
  p2[b*128 + c] = make_float2(sc, bea[c] - sm[b*G_+g]*sc);
}

// ---------------- unified MFMA GEMM body: Y[o][p] = W*X + bias, 64 pts x 128 out ----------------
#define ST_COPY 0
#define ST_GN   1
#define ST_POS  2
#define EP_PM    0
#define EP_QKS   1
#define EP_F32CM 2

template<int STAGE>
__device__ __forceinline__ void stage_x(ushort* xs,
    const ushort* __restrict__ Xb, const float* __restrict__ prm,
    const float4* __restrict__ pt4, const int* __restrict__ idx, int p0, int b)
{
  int tid = threadIdx.x;
  int row = tid & 63, cc = tid >> 6;
  if constexpr (STAGE == ST_COPY){
    const ushort* src = Xb + (size_t)(p0+row)*C_ + cc*32;
    #pragma unroll
    for (int q = 0; q < 4; q++){
      s16x8 v8 = *(const s16x8*)(src + q*8);
      int sl = (cc*4+q) ^ (row&7);
      *(s16x8*)(xs + row*C_ + sl*8) = v8;
    }
  } else if constexpr (STAGE == ST_GN){
    const ushort* src = Xb + (size_t)(p0+row)*C_ + cc*32;
    const float2* pr = (const float2*)prm + b*128;
    #pragma unroll
    for (int q = 0; q < 4; q++){
      s16x8 v8 = *(const s16x8*)(src + q*8);
      s16x8 o8;
      #pragma unroll
      for (int i = 0; i < 8; i++){
        int c = cc*32 + q*8 + i;
        float2 s2 = pr[c];
        o8[i] = f2b(leakyf(b2f(v8[i])*s2.x + s2.y));
      }
      int sl = (cc*4+q) ^ (row&7);
      *(s16x8*)(xs + row*C_ + sl*8) = o8;
    }
  } else { // ST_POS
    int p = p0 + row;
    int ng = p >> 4;
    int j = idx[p];
    float4 pj = pt4[(b<<13) + j], pn = pt4[ng];
    float rx = pj.x - pn.x, ry = pj.y - pn.y, rz = pj.z - pn.z;
    const float4* pr = (const float4*)prm + b*128;
    #pragma unroll
    for (int q = 0; q < 4; q++){
      s16x8 o8;
      #pragma unroll
      for (int i = 0; i < 8; i++){
        int c = cc*32 + q*8 + i;
        float4 s4 = pr[c];
        o8[i] = f2b(leakyf(fmaf(s4.x, rx, fmaf(s4.y, ry, fmaf(s4.z, rz, s4.w)))));
      }
      int sl = (cc*4+q) ^ (row&7);
      *(s16x8*)(xs + row*C_ + sl*8) = o8;
    }
  }
}

__device__ __forceinline__ void load_afr(s16x8 afr[2][4], const float* __restrict__ W, int wid, int lm, int lh){
  #pragma unroll
  for (int t = 0; t < 2; t++){
    int T = wid*2 + t;
    #pragma unroll
    for (int ks = 0; ks < 4; ks++){
      const float* wr = W + (size_t)(T*16 + lm)*C_ + ks*32 + lh*8;
      float4 w0 = *(const float4*)wr;
      float4 w1 = *(const float4*)(wr+4);
      s16x8 a;
      a[0]=f2b(w0.x); a[1]=f2b(w0.y); a[2]=f2b(w0.z); a[3]=f2b(w0.w);
      a[4]=f2b(w1.x); a[5]=f2b(w1.y); a[6]=f2b(w1.z); a[7]=f2b(w1.w);
      afr[t][ks] = a;
    }
  }
}

__device__ __forceinline__ void mfma_tile(f32x4 acc[2][4], const s16x8 afr[2][4],
    const ushort* xs, const float* __restrict__ bias, int wid, int lm, int lh)
{
  #pragma unroll
  for (int t = 0; t < 2; t++){
    f32x4 bs = *(const f32x4*)(bias + (wid*2+t)*16 + lh*4);
    #pragma unroll
    for (int ps = 0; ps < 4; ps++) acc[t][ps] = bs;
  }
  #pragma unroll
  for (int ps = 0; ps < 4; ps++){
    int row = ps*16 + lm;
    s16x8 bf[4];
    #pragma unroll
    for (int ks = 0; ks < 4; ks++){
      int sl = (ks*4+lh) ^ (row&7);
      bf[ks] = *(const s16x8*)(xs + row*C_ + sl*8);
    }
    #pragma unroll
    for (int ks = 0; ks < 4; ks++){
      #pragma unroll
      for (int t = 0; t < 2; t++)
        acc[t][ps] = __builtin_amdgcn_mfma_f32_16x16x32_bf16(afr[t][ks], bf[ks], acc[t][ps], 0,0,0);
    }
  }
}

template<int STAGE, int EPI>
__device__ __forceinline__ void mgemm_body(ushort* xs, float* sblk,
    const ushort* __restrict__ Xb, const float* __restrict__ W, const float* __restrict__ bias,
    const float* __restrict__ prm, const float4* __restrict__ pt4, const int* __restrict__ idx,
    const ushort* __restrict__ Aq, const ushort* __restrict__ Ak,
    void* __restrict__ Y, float* __restrict__ gsum, float* __restrict__ gssq, int bsh, int bx)
{
  int tid = threadIdx.x;
  int l = tid & 63, wid = tid >> 6;
  int lm = l & 15, lh = l >> 4;
  int p0 = bx * 64;
  int b = p0 >> bsh;

  if (tid < 16) sblk[tid] = 0.f;

  s16x8 afr[2][4];
  load_afr(afr, W, wid, lm, lh);
  stage_x<STAGE>(xs, Xb, prm, pt4, idx, p0, b);
  __syncthreads();

  f32x4 acc[2][4];
  mfma_tile(acc, afr, xs, bias, wid, lm, lh);

  // ---- epilogue ----
  float gs[2] = {0.f,0.f}, gq[2] = {0.f,0.f};
  #pragma unroll
  for (int t = 0; t < 2; t++){
    int T = wid*2 + t;
    int o0 = T*16 + lh*4;
    #pragma unroll
    for (int ps = 0; ps < 4; ps++){
      int p = p0 + ps*16 + lm;
      if constexpr (EPI == EP_PM){
        s16x4 r4;
        #pragma unroll
        for (int r = 0; r < 4; r++) r4[r] = f2b(acc[t][ps][r]);
        *(s16x4*)((ushort*)Y + (size_t)p*C_ + o0) = r4;
      } else if constexpr (EPI == EP_QKS){
        int ng = p >> 4;
        int j = idx[p];
        s16x4 aq4 = *(const s16x4*)(Aq + (size_t)ng*C_ + o0);
        s16x4 ak4 = *(const s16x4*)(Ak + ((size_t)(b<<13)+j)*C_ + o0);
        s16x4 r4;
        #pragma unroll
        for (int r = 0; r < 4; r++){
          float v = acc[t][ps][r] + b2f(aq4[r]) - b2f(ak4[r]);
          r4[r] = f2b(v);
          gs[t] += v; gq[t] += v*v;
        }
        *(s16x4*)((ushort*)Y + (size_t)p*C_ + o0) = r4;
      } else { // EP_F32CM
        float* yf = (float*)Y;
        #pragma unroll
        for (int r = 0; r < 4; r++){
          float v = acc[t][ps][r];
          yf[(size_t)(o0+r)*BN_ + p] = v;
          gs[t] += v; gq[t] += v*v;
        }
      }
    }
  }

  if constexpr (EPI == EP_QKS || EPI == EP_F32CM){
    #pragma unroll
    for (int t = 0; t < 2; t++){
      float s = gs[t], q = gq[t];
      #pragma unroll
      for (int mk = 32; mk; mk >>= 1){ s += __shfl_xor(s, mk, 64); q += __shfl_xor(q, mk, 64); }
      if (l == 0){
        int T = wid*2 + t;
        atomicAdd(&sblk[T], s); atomicAdd(&sblk[8+T], q);
      }
    }
    __syncthreads();
    if (tid < 8){
      atomicAdd(&gsum[b*G_ + tid], sblk[tid]);
      atomicAdd(&gssq[b*G_ + tid], sblk[8+tid]);
    }
  }
}

template<int STAGE, int EPI>
__global__ __launch_bounds__(256) void mgemm_kernel(
    const ushort* __restrict__ Xb, const float* __restrict__ W, const float* __restrict__ bias,
    const float* __restrict__ prm, const float4* __restrict__ pt4, const int* __restrict__ idx,
    const ushort* __restrict__ Aq, const ushort* __restrict__ Ak,
    void* __restrict__ Y, float* __restrict__ gsum, float* __restrict__ gssq, int bsh)
{
  __shared__ ushort xs[64*128];
  __shared__ float sblk[16];
  mgemm_body<STAGE,EPI>(xs, sblk, Xb, W, bias, prm, pt4, idx, Aq, Ak, Y, gsum, gssq, bsh, blockIdx.x);
}

// v / Aq / Ak in one launch (gridDim.y = 3)
__global__ __launch_bounds__(256) void qkv_kernel(const ushort* __restrict__ nfb,
    const float* __restrict__ Wv, const float* __restrict__ bv,
    const float* __restrict__ Wqa, const float* __restrict__ bqa,
    const float* __restrict__ Wka, const float* __restrict__ bka,
    ushort* __restrict__ vb, ushort* __restrict__ Aqb, ushort* __restrict__ Akb)
{
  __shared__ ushort xs[64*128];
  __shared__ float sblk[16];
  if (blockIdx.y == 0)
    mgemm_body<ST_COPY,EP_PM>(xs, sblk, nfb, Wv, bv, nullptr, nullptr, nullptr, nullptr, nullptr, vb, nullptr, nullptr, 13, blockIdx.x);
  else if (blockIdx.y == 1)
    mgemm_body<ST_COPY,EP_PM>(xs, sblk, nfb, Wqa, bqa, nullptr, nullptr, nullptr, nullptr, nullptr, Aqb, nullptr, nullptr, 13, blockIdx.x);
  else
    mgemm_body<ST_COPY,EP_PM>(xs, sblk, nfb, Wka, bka, nullptr, nullptr, nullptr, nullptr, nullptr, Akb, nullptr, nullptr, 13, blockIdx.x);
}

// ---------------- fused: GN(att1) -> W_att2 GEMM -> softmax(k) -> PV + residual ----------------
__global__ __launch_bounds__(256) void fatt_kernel(const ushort* __restrict__ Xb /*att1 PM*/,
    const float* __restrict__ W /*W_att2*/, const float* __restrict__ bias /*b_att2*/,
    const float* __restrict__ prm /*attPrm*/, const int* __restrict__ idx,
    const ushort* __restrict__ vb, const ushort* __restrict__ nfb, ushort* __restrict__ outb)
{
  __shared__ ushort xs[64*128];
  int tid = threadIdx.x;
  int l = tid & 63, wid = tid >> 6;
  int lm = l & 15, lh = l >> 4;
  int p0 = blockIdx.x * 64;
  int b = p0 >> 17;

  // prefetch V gathers first (latency overlaps staging global loads + transform + MFMA)
  s16x4 vpre[2][4];
  #pragma unroll
  for (int ps = 0; ps < 4; ps++){
    int p = p0 + ps*16 + lm;
    int j = idx[p];
    const ushort* vr = vb + ((size_t)(b<<13)+j)*C_ + lh*4;
    #pragma unroll
    for (int t = 0; t < 2; t++)
      vpre[t][ps] = *(const s16x4*)(vr + (wid*2+t)*16);
  }

  s16x8 afr[2][4];
  load_afr(afr, W, wid, lm, lh);
  stage_x<ST_GN>(xs, Xb, prm, nullptr, nullptr, p0, b);
  __syncthreads();

  f32x4 acc[2][4];
  mfma_tile(acc, afr, xs, bias, wid, lm, lh);

  // softmax over k (lm) + PV + residual — DPP row reductions (VALU-only)
  #pragma unroll
  for (int t = 0; t < 2; t++){
    int o0 = (wid*2+t)*16 + lh*4;
    #pragma unroll
    for (int ps = 0; ps < 4; ps++){
      s16x4 v4 = vpre[t][ps];
      f32x4 e, pv;
      #pragma unroll
      for (int r = 0; r < 4; r++){
        float ev = __expf(acc[t][ps][r]);
        e[r] = ev;
        pv[r] = ev * b2f(v4[r]);
      }
      #pragma unroll
      for (int r = 0; r < 4; r++){
        e[r]  = red16(e[r]);
        pv[r] = red16(pv[r]);
      }
      if (lm == 0){
        int n = (p0 + ps*16) >> 4;
        s16x4 n4 = *(const s16x4*)(nfb + (size_t)n*C_ + o0);
        s16x4 o4;
        #pragma unroll
        for (int r = 0; r < 4; r++) o4[r] = f2b(pv[r]/e[r] + b2f(n4[r]));
        *(s16x4*)(outb + (size_t)n*C_ + o0) = o4;
      }
    }
  }
}

// ---------------- final: inline post-finalize + GN + leaky (out1 col-major [C][BN]) ----------------
__global__ __launch_bounds__(256) void final_kernel(const float* __restrict__ out1,
    const float* __restrict__ gsum, const float* __restrict__ gssq,
    const float* __restrict__ g, const float* __restrict__ be, float* __restrict__ out){
  int e = blockIdx.x*256 + threadIdx.x;
  int b = e >> 20;
  int c = (e >> 13) & (C_-1);
  int n = e & (N_-1);
  int gi = b*G_ + (c >> 4);
  const float invcnt = 1.0f/(float)(16*N_);
  float m = gsum[gi]*invcnt;
  float var = gssq[gi]*invcnt - m*m;
  var = fmaxf(var, 0.f);
  float r = rsqrtf(var + EPSV);
  float v = (out1[(size_t)c*BN_ + b*N_ + n] - m) * r;
  v = v*g[c] + be[c];
  out[e] = leakyf(v);
}

extern "C" void kernel_launch(void* const* d_in, const int* in_sizes, int n_in,
                              void* d_out, int out_size, void* d_ws, size_t ws_size,
                              hipStream_t stream) {
  const float* xyz    = (const float*)d_in[0];
  const float* feat   = (const float*)d_in[1];
  const float* W_pre  = (const float*)d_in[2];
  const float* b_pre  = (const float*)d_in[3];
  const float* W_pos1 = (const float*)d_in[4];
  const float* b_pos1 = (const float*)d_in[5];
  const float* g_pos1 = (const float*)d_in[6];
  const float* be_pos1= (const float*)d_in[7];
  const float* W_pos2 = (const float*)d_in[8];
  const float* b_pos2 = (const float*)d_in[9];
  const float* W_q    = (const float*)d_in[10];
  const float* b_q    = (const float*)d_in[11];
  const float* W_k    = (const float*)d_in[12];
  const float* b_k    = (const float*)d_in[13];
  const float* W_v    = (const float*)d_in[14];
  const float* b_v    = (const float*)d_in[15];
  const float* W_att1 = (const float*)d_in[16];
  const float* b_att1 = (const float*)d_in[17];
  const float* g_att1 = (const float*)d_in[18];
  const float* be_att1= (const float*)d_in[19];
  const float* W_att2 = (const float*)d_in[20];
  const float* b_att2 = (const float*)d_in[21];
  const float* W_post = (const float*)d_in[22];
  const float* b_post = (const float*)d_in[23];
  const float* g_post = (const float*)d_in[24];
  const float* be_post= (const float*)d_in[25];

  char* w = (char*)d_ws;
  float4* pt4 = (float4*)w;            w += sizeof(float4)*BN_;
  int* idx = (int*)w;                  w += sizeof(int)*BNK_;
  ushort* fb   = (ushort*)w;           w += (size_t)2*BN_*C_;
  ushort* nfb  = (ushort*)w;           w += (size_t)2*BN_*C_;
  ushort* vb   = (ushort*)w;           w += (size_t)2*BN_*C_;
  ushort* Aqb  = (ushort*)w;           w += (size_t)2*BN_*C_;
  ushort* Akb  = (ushort*)w;           w += (size_t)2*BN_*C_;
  ushort* outb = (ushort*)w;           w += (size_t)2*BN_*C_;
  float* out1  = (float*)w;            w += (size_t)4*BN_*C_;
  ushort* bufA = (ushort*)w;           w += (size_t)2*BNK_*C_;           // att1 PM
  float* Wf    = (float*)w;            w += sizeof(float)*C_*C_;
  float* Wqa   = (float*)w;            w += sizeof(float)*C_*C_;
  float* Wka   = (float*)w;            w += sizeof(float)*C_*C_;
  float* bG1   = (float*)w;            w += 512;
  float* bqa   = (float*)w;            w += 512;
  float* bka   = (float*)w;            w += 512;
  float* posPrm= (float*)w;            w += sizeof(float)*1024;
  float* attPrm= (float*)w;            w += sizeof(float)*512;
  float* stats = (float*)w;            w += 1024;
  int* cellCnt = (int*)w;              w += sizeof(int)*2*NC_;
  int* cellStart=(int*)w;              w += sizeof(int)*(2*NC_+1);
  int* cellCur = (int*)w;              w += sizeof(int)*2*NC_;
  float4* spts = (float4*)w;           w += sizeof(float4)*BN_;
  int* sidx    = (int*)w;              w += sizeof(int)*BN_;

  float* pos_sum = stats +  0, *pos_ssq = stats + 16;
  float* att_sum = stats + 64, *att_ssq = stats + 80;
  float* post_sum= stats +128, *post_ssq= stats +144;

  hipMemsetAsync(stats, 0, 1024, stream);
  hipMemsetAsync(cellCnt, 0, sizeof(int)*2*NC_, stream);

  pack_featb_kernel<<<BN_/256, 256, 0, stream>>>(xyz, feat, pt4, fb, cellCnt);
  scan_kernel<<<1, 1024, 0, stream>>>(cellCnt, cellStart, cellCur);
  scatter_kernel<<<BN_/256, 256, 0, stream>>>(pt4, cellCur, spts, sidx);
  knn_kernel<<<BN_/8, 512, 0, stream>>>(pt4, spts, sidx, cellStart, idx);

  // fused weights / biases (one launch)
  setup_kernel<<<193, 256, 0, stream>>>(W_att1, W_pos2, W_q, W_k, b_pos2, b_att1, b_q, b_k,
      Wf, Wqa, Wka, bG1, bqa, bka);

  // nf = W_pre*feat + b
  mgemm_kernel<ST_COPY,EP_PM><<<BN_/64, 256, 0, stream>>>(fb, W_pre, b_pre, nullptr, nullptr, nullptr,
      nullptr, nullptr, nfb, nullptr, nullptr, 13);
  // v, Aq, Ak (one launch)
  qkv_kernel<<<dim3(BN_/64, 3), 256, 0, stream>>>(nfb, W_v, b_v, Wqa, bqa, Wka, bka, vb, Aqb, Akb);

  // pos GN stats -> folded params
  pos_stats_kernel<<<BNK_/256, 256, 0, stream>>>(pt4, idx, W_pos1, b_pos1, pos_sum, pos_ssq);
  posfin_kernel<<<1, 256, 0, stream>>>(pos_sum, pos_ssq, W_pos1, b_pos1, g_pos1, be_pos1, posPrm,
      1.0f/(float)(16.0*NK_));

  // G1: att1 = Wf*posn + bG1 + Aq[n] - Ak[j]  (+ stats)  -> bufA
  mgemm_kernel<ST_POS,EP_QKS><<<BNK_/64, 256, 0, stream>>>(nullptr, Wf, bG1, posPrm, pt4, idx,
      Aqb, Akb, bufA, att_sum, att_ssq, 17);
  attfin_kernel<<<1, 256, 0, stream>>>(att_sum, att_ssq, g_att1, be_att1, attPrm, 1.0f/(float)(16.0*NK_));

  // fused G2 + softmax + PV + residual
  fatt_kernel<<<BNK_/64, 256, 0, stream>>>(bufA, W_att2, b_att2, attPrm, idx, vb, nfb, outb);

  // post conv + stats (f32 col-major)
  mgemm_kernel<ST_COPY,EP_F32CM><<<BN_/64, 256, 0, stream>>>(outb, W_post, b_post, nullptr, nullptr, nullptr,
      nullptr, nullptr, out1, post_sum, post_ssq, 13);
  final_kernel<<<(B_*CN_)/256, 256, 0, stream>>>(out1, post_sum, post_ssq, g_post, be_post, (float*)d_out);
}

// Round 15
// 337.396 us; speedup vs baseline: 1.0544x; 1.0544x over previous
//
#include <hip/hip_runtime.h>
#include <hip/hip_bf16.h>
#include <float.h>

#define B_ 2
#define N_ 8192
#define C_ 128
#define K_ 16
#define G_ 8
#define NK_ (N_*K_)     // 131072
#define BN_ (B_*N_)     // 16384
#define BNK_ (B_*NK_)   // 262144
#define CN_ (C_*N_)
#define NEG 0.1f
#define EPSV 1e-5f

// KNN grid: 24^3 cells, h=0.5, box [-6,6]
#define GR_ 24
#define NC_ (GR_*GR_*GR_)    // 13824 cells per batch
#define GLOF -6.0f
#define GHF 0.5f
#define KNN_MARGIN 2e-4f
#define EMPTY_KEY 0x7FEFFFFFFFFFFFFFull

typedef __attribute__((ext_vector_type(4))) float f32x4;
typedef __attribute__((ext_vector_type(8))) short s16x8;
typedef __attribute__((ext_vector_type(4))) short s16x4;

__device__ __forceinline__ float leakyf(float x){ return x >= 0.f ? x : NEG*x; }
__device__ __forceinline__ short f2b(float x){
  union { __hip_bfloat16 b; short s; } u; u.b = __float2bfloat16(x); return u.s;
}
__device__ __forceinline__ float b2f(short s){
  union { __hip_bfloat16 b; short s; } u; u.s = s; return __bfloat162float(u.b);
}

// row_shr:1 within 16-lane rows (list lives in lanes 0..15 -> row-local)
__device__ __forceinline__ int dpp_shr1_i(int x){
  return __builtin_amdgcn_update_dpp(x, x, 0x111, 0xF, 0xF, false);
}
__device__ __forceinline__ unsigned long long dpp_shr1_u64(unsigned long long x){
  union { unsigned long long q; int i[2]; } u; u.q = x;
  u.i[0] = dpp_shr1_i(u.i[0]);
  u.i[1] = dpp_shr1_i(u.i[1]);
  return u.q;
}
__device__ __forceinline__ unsigned long long readlane_u64(unsigned long long x, int l){
  union { unsigned long long q; int i[2]; } u; u.q = x;
  union { unsigned long long q; int i[2]; } r;
  r.i[0] = __builtin_amdgcn_readlane(u.i[0], l);
  r.i[1] = __builtin_amdgcn_readlane(u.i[1], l);
  return r.q;
}
// sort key: d2 (clamped >=0) bits, low 13 mantissa bits replaced by idx.
__device__ __forceinline__ unsigned long long d2key(double d2, int idx){
  d2 = fmax(d2, 0.0);
  union { double d; unsigned long long q; } u; u.d = d2;
  return (u.q & ~0x1FFFull) | (unsigned long long)idx;
}
__device__ __forceinline__ double key_upper_d2(unsigned long long k){
  union { unsigned long long q; double d; } u; u.q = k | 0x1FFFull;   // round up: conservative
  return u.d;
}
__device__ __forceinline__ int cell1(float x){
  int c = (int)floorf((x - GLOF)*(1.0f/GHF));
  return min(max(c, 0), GR_-1);
}

// DPP float move (ctrl as template constant; all rows/banks, bound_ctrl=1)
template<int CTRL>
__device__ __forceinline__ float dppf(float x){
  union { float f; int i; } u; u.f = x;
  u.i = __builtin_amdgcn_update_dpp(0, u.i, CTRL, 0xF, 0xF, true);
  return u.f;
}
// 16-lane row sum, identical pairing to xor1/2/4/8 butterfly (bit-identical result)
__device__ __forceinline__ float red16(float x){
  x += dppf<0xB1>(x);    // quad_perm [1,0,3,2] : xor 1
  x += dppf<0x4E>(x);    // quad_perm [2,3,0,1] : xor 2
  x += dppf<0x141>(x);   // row_half_mirror     : xor 4
  x += dppf<0x140>(x);   // row_mirror          : xor 8
  return x;
}

// ---------------- pack xyz -> float4 (w=|p|^2 fp32) + feat -> bf16 PM + cell histogram ----------------
__global__ __launch_bounds__(256) void pack_featb_kernel(const float* __restrict__ xyz,
    const float* __restrict__ feat, float4* __restrict__ pt4, ushort* __restrict__ fb,
    int* __restrict__ cellCnt){
  int e = blockIdx.x*256 + threadIdx.x;
  int b = e >> 13, n = e & (N_-1);
  const float* xb = xyz + b*3*N_;
  float x = xb[n], y = xb[N_+n], z = xb[2*N_+n];
  pt4[e] = make_float4(x, y, z, x*x + y*y + z*z);
  atomicAdd(&cellCnt[b*NC_ + (cell1(z)*GR_ + cell1(y))*GR_ + cell1(x)], 1);
  const float* xin = feat + b*CN_ + n;
  #pragma unroll
  for (int c0 = 0; c0 < C_; c0 += 8){
    s16x8 o8;
    #pragma unroll
    for (int i = 0; i < 8; i++) o8[i] = f2b(xin[(size_t)(c0+i)*N_]);
    *(s16x8*)(fb + (size_t)e*C_ + c0) = o8;
  }
}

// ---------------- exclusive prefix scan over 2*NC_ = 27648 cells (single block, 27/thread) ----------------
__global__ __launch_bounds__(1024) void scan_kernel(const int* __restrict__ cnt,
    int* __restrict__ cellStart, int* __restrict__ cellCur){
  __shared__ int bs[1024];
  int t = threadIdx.x;
  int base = t*27;
  int s = 0;
  for (int i = 0; i < 27; i++) s += cnt[base+i];
  bs[t] = s;
  __syncthreads();
  for (int off = 1; off < 1024; off <<= 1){
    int v = (t >= off) ? bs[t-off] : 0;
    __syncthreads();
    bs[t] += v;
    __syncthreads();
  }
  int run = (t == 0) ? 0 : bs[t-1];
  for (int i = 0; i < 27; i++){
    cellStart[base+i] = run;
    cellCur[base+i]  = run;
    run += cnt[base+i];
  }
  if (t == 1023) cellStart[2*NC_] = BN_;
}

// ---------------- scatter points into cell-sorted order ----------------
__global__ __launch_bounds__(256) void scatter_kernel(const float4* __restrict__ pt4,
    int* __restrict__ cellCur, float4* __restrict__ spts, int* __restrict__ sidx){
  int e = blockIdx.x*256 + threadIdx.x;
  int b = e >> 13;
  float4 p = pt4[e];
  int cid = b*NC_ + (cell1(p.z)*GR_ + cell1(p.y))*GR_ + cell1(p.x);
  int slot = atomicAdd(&cellCur[cid], 1);
  spts[slot] = p;
  sidx[slot] = e & (N_-1);
}

// ---------------- KNN hybrid: ring-1 grid pass; brute-force fallback (R13-proven) ----------------
__global__ __launch_bounds__(512) void knn_kernel(const float4* __restrict__ pt4,
    const float4* __restrict__ spts, const int* __restrict__ sidx,
    const int* __restrict__ cellStart, int* __restrict__ idxo){
  int lane = threadIdx.x & 63, wid = threadIdx.x >> 6;
  int qg = blockIdx.x*8 + wid;           // sorted slot
  int b = qg >> 13;
  float4 qp = spts[qg];
  int nq = sidx[qg];                     // original point index within batch
  double qx = qp.x, qy = qp.y, qz = qp.z;
  double qsq = qx*qx + qy*qy + qz*qz;
  float qx2 = -2.f*qp.x, qy2 = -2.f*qp.y, qz2 = -2.f*qp.z;
  unsigned long long mykey = EMPTY_KEY;  // lanes 0..15: sorted top-16 keys
  float cmpv = FLT_MAX;
  int ci = cell1(qp.x), cj = cell1(qp.y), ck = cell1(qp.z);

  auto process = [&](unsigned long long m, unsigned long long keyv){
    while (m){
      int src = __ffsll(m) - 1; m &= m - 1;
      unsigned long long kn = readlane_u64(keyv, src);
      bool less = kn < mykey;
      unsigned long long bm = __ballot(less) & 0xFFFFull;
      if (bm){
        int pos = __ffsll(bm) - 1;
        unsigned long long pk = dpp_shr1_u64(mykey);
        if (lane < 16){
          if (lane > pos) mykey = pk;
          else if (lane == pos) mykey = kn;
        }
      }
    }
  };

  auto do_range = [&](int cid0, int cid1){
    int s = cellStart[cid0], e = cellStart[cid1+1];
    for (int off = s; off < e; off += 64){
      int t = off + lane;
      bool valid = t < e;
      float4 pp = make_float4(0.f, 0.f, 0.f, 3.0e38f);
      int oi = 0;
      if (valid){ pp = spts[t]; oi = sidx[t]; }
      float f = fmaf(pp.x, qx2, fmaf(pp.y, qy2, fmaf(pp.z, qz2, pp.w)));
      unsigned long long m = __ballot(valid && (f < cmpv));
      if (m){
        double px = pp.x, py = pp.y, pz = pp.z;
        double psq = px*px + py*py + pz*pz;
        double dot = qx*px + qy*py + qz*pz;
        process(m, d2key(qsq + psq - 2.0*dot, oi));
        cmpv = fminf(cmpv, (float)(key_upper_d2(readlane_u64(mykey, 15)) - qsq) + KNN_MARGIN);
      }
    }
  };

  // phase 1: ring 0+1 as 9 contiguous x-runs; own row first for fast threshold convergence
  int x0 = max(ci-1, 0), x1 = min(ci+1, GR_-1);
  int cbase = b*NC_;
  do_range(cbase + (ck*GR_ + cj)*GR_ + x0, cbase + (ck*GR_ + cj)*GR_ + x1);
  for (int dz = -1; dz <= 1; dz++){
    int z = ck + dz; if (z < 0 || z >= GR_) continue;
    for (int dy = -1; dy <= 1; dy++){
      int y = cj + dy; if (y < 0 || y >= GR_) continue;
      if ((dy | dz) == 0) continue;
      do_range(cbase + (z*GR_ + y)*GR_ + x0, cbase + (z*GR_ + y)*GR_ + x1);
    }
  }

  // exact coverage bound: points outside ring-1 are >= h away (cells exact in fp32)
  double thr_up = key_upper_d2(readlane_u64(mykey, 15));
  if (thr_up > (double)GHF*(double)GHF){
    // phase 2: brute-force over original (spatially random) order; reset list, keep filter
    mykey = EMPTY_KEY;
    const float4* pts = pt4 + (b << 13);
    for (int t0 = 0; t0 < N_; t0 += 64){
      float4 pp = pts[t0 + lane];
      float f = fmaf(pp.x, qx2, fmaf(pp.y, qy2, fmaf(pp.z, qz2, pp.w)));
      unsigned long long m = __ballot(f < cmpv);
      if (m){
        double px = pp.x, py = pp.y, pz = pp.z;
        double psq = px*px + py*py + pz*pz;
        double dot = qx*px + qy*py + qz*pz;
        process(m, d2key(qsq + psq - 2.0*dot, t0 + lane));
        cmpv = fminf(cmpv, (float)(key_upper_d2(readlane_u64(mykey, 15)) - qsq) + KNN_MARGIN);
      }
    }
  }
  if (lane < 16) idxo[((size_t)(b<<13) + nq)*K_ + lane] = (int)(mykey & 0x1FFFull);
}

// ---------------- setup: fused weights (3 x 128^3) + fused biases ----------------
__global__ __launch_bounds__(256) void setup_kernel(const float* __restrict__ W_att1,
    const float* __restrict__ W_pos2, const float* __restrict__ W_q, const float* __restrict__ W_k,
    const float* __restrict__ b_pos2, const float* __restrict__ b_att1,
    const float* __restrict__ b_q, const float* __restrict__ b_k,
    float* __restrict__ Wf, float* __restrict__ Wqa, float* __restrict__ Wka,
    float* __restrict__ bG1, float* __restrict__ bqa, float* __restrict__ bka){
  int bx = blockIdx.x;
  if (bx < 192){
    int which = bx >> 6;
    const float* Bm = which==0 ? W_pos2 : (which==1 ? W_q : W_k);
    float* Cm = which==0 ? Wf : (which==1 ? Wqa : Wka);
    int e = (bx & 63)*256 + threadIdx.x;
    int o = e >> 7, c = e & 127;
    float s = 0.f;
    #pragma unroll 8
    for (int m = 0; m < 128; m++) s += W_att1[o*128+m]*Bm[m*128+c];
    Cm[e] = s;
  } else {
    for (int t = threadIdx.x; t < 384; t += 256){
      int which = t >> 7, o = t & 127;
      const float* v = which==0 ? b_pos2 : (which==1 ? b_q : b_k);
      float* out = which==0 ? bG1 : (which==1 ? bqa : bka);
      float s = which==0 ? b_att1[o] : 0.f;
      for (int m = 0; m < 128; m++) s += W_att1[o*128+m]*v[m];
      out[o] = s;
    }
  }
}

// ---------------- pos moments: per-batch [R(3), S_diag(3), S_off(3)] over rel = pj - pn ----------------
__global__ __launch_bounds__(256) void posmom_kernel(const float4* __restrict__ pt4,
    const int* __restrict__ idx, float* __restrict__ mom){
  __shared__ float ls[9];
  if (threadIdx.x < 9) ls[threadIdx.x] = 0.f;
  __syncthreads();
  int p = blockIdx.x*256 + threadIdx.x;
  int b = p >> 17;
  int n = p >> 4;
  int j = idx[p];
  float4 pj = pt4[(b<<13) + j], pn = pt4[n];
  float rx = pj.x - pn.x, ry = pj.y - pn.y, rz = pj.z - pn.z;
  float m9[9] = { rx, ry, rz, rx*rx, ry*ry, rz*rz, rx*ry, rx*rz, ry*rz };
  #pragma unroll
  for (int i = 0; i < 9; i++){
    float s = m9[i];
    #pragma unroll
    for (int mk = 32; mk; mk >>= 1) s += __shfl_xor(s, mk, 64);
    if ((threadIdx.x & 63) == 0) atomicAdd(&ls[i], s);
  }
  __syncthreads();
  if (threadIdx.x < 9) atomicAdd(&mom[b*9 + threadIdx.x], ls[threadIdx.x]);
}

// ---------------- pos finalize from moments + folded GN params (float4: sx,sy,sz,so) ----------------
// sum_c v = W_c.R + b_c*M ; sum_c v^2 = W_c^T S W_c + 2 b_c (W_c.R) + b_c^2 M  (linear map exactness)
__global__ void posfin_kernel(const float* __restrict__ mom,
    const float* __restrict__ W1, const float* __restrict__ b1,
    const float* __restrict__ g1, const float* __restrict__ be1, float* __restrict__ prm){
  int i = threadIdx.x;           // 256: b = i>>7, c = i&127
  int b = i >> 7, c = i & 127;
  const float* M = mom + b*9;
  float wx = W1[3*c], wy = W1[3*c+1], wz = W1[3*c+2], bb = b1[c];
  const float cnt = (float)NK_;
  float wr = wx*M[0] + wy*M[1] + wz*M[2];
  float s_c = wr + bb*cnt;
  float q_c = wx*wx*M[3] + wy*wy*M[4] + wz*wz*M[5]
            + 2.f*(wx*wy*M[6] + wx*wz*M[7] + wy*wz*M[8])
            + 2.f*bb*wr + bb*bb*cnt;
  // reduce over the 16 channels of each group (16 consecutive lanes, same wave)
  #pragma unroll
  for (int mk = 1; mk < 16; mk <<= 1){
    s_c += __shfl_xor(s_c, mk, 64);
    q_c += __shfl_xor(q_c, mk, 64);
  }
  const float invcnt = 1.0f/(16.0f*(float)NK_);
  float m = s_c*invcnt;
  float var = q_c*invcnt - m*m;
  var = fmaxf(var, 0.f);
  float r = rsqrtf(var + EPSV);
  float rs = r*g1[c];
  float4* p4 = (float4*)prm;
  p4[b*128 + c] = make_float4(wx*rs, wy*rs, wz*rs, (bb-m)*rs + be1[c]);
}

// ---------------- att finalize + folded scale/shift (interleaved float2: sc,sh) ----------------
__global__ void attfin_kernel(const float* __restrict__ gsum, const float* __restrict__ gssq,
    const float* __restrict__ ga, const float* __restrict__ bea, float* __restrict__ prm, float invcnt){
  __shared__ float sm[16], sr[16];
  int i = threadIdx.x;
  if (i < 16){
    float m = gsum[i]*invcnt;
    float v = gssq[i]*invcnt - m*m;
    v = fmaxf(v, 0.f);
    sm[i] = m; sr[i] = rsqrtf(v + EPSV);
  }
  __syncthreads();
  int b = i >> 7, c = i & 127, g = c >> 4;
  float sc = ga[c]*sr[b*G_+g];
  float2* p2 = (float2*)prm;
  p2[b*128 + c] = make_float2(sc, bea[c] - sm[b*G_+g]*sc);
}

// ---------------- unified MFMA GEMM body: Y[o][p] = W*X + bias, 64 pts x 128 out ----------------
#define ST_COPY 0
#define ST_GN   1
#define ST_POS  2
#define EP_PM    0
#define EP_QKS   1
#define EP_F32CM 2

template<int STAGE>
__device__ __forceinline__ void stage_x(ushort* xs,
    const ushort* __restrict__ Xb, const float* __restrict__ prm,
    const float4* __restrict__ pt4, const int* __restrict__ idx, int p0, int b)
{
  int tid = threadIdx.x;
  int row = tid & 63, cc = tid >> 6;
  if constexpr (STAGE == ST_COPY){
    const ushort* src = Xb + (size_t)(p0+row)*C_ + cc*32;
    #pragma unroll
    for (int q = 0; q < 4; q++){
      s16x8 v8 = *(const s16x8*)(src + q*8);
      int sl = (cc*4+q) ^ (row&7);
      *(s16x8*)(xs + row*C_ + sl*8) = v8;
    }
  } else if constexpr (STAGE == ST_GN){
    const ushort* src = Xb + (size_t)(p0+row)*C_ + cc*32;
    const float2* pr = (const float2*)prm + b*128;
    #pragma unroll
    for (int q = 0; q < 4; q++){
      s16x8 v8 = *(const s16x8*)(src + q*8);
      s16x8 o8;
      #pragma unroll
      for (int i = 0; i < 8; i++){
        int c = cc*32 + q*8 + i;
        float2 s2 = pr[c];
        o8[i] = f2b(leakyf(b2f(v8[i])*s2.x + s2.y));
      }
      int sl = (cc*4+q) ^ (row&7);
      *(s16x8*)(xs + row*C_ + sl*8) = o8;
    }
  } else { // ST_POS
    int p = p0 + row;
    int ng = p >> 4;
    int j = idx[p];
    float4 pj = pt4[(b<<13) + j], pn = pt4[ng];
    float rx = pj.x - pn.x, ry = pj.y - pn.y, rz = pj.z - pn.z;
    const float4* pr = (const float4*)prm + b*128;
    #pragma unroll
    for (int q = 0; q < 4; q++){
      s16x8 o8;
      #pragma unroll
      for (int i = 0; i < 8; i++){
        int c = cc*32 + q*8 + i;
        float4 s4 = pr[c];
        o8[i] = f2b(leakyf(fmaf(s4.x, rx, fmaf(s4.y, ry, fmaf(s4.z, rz, s4.w)))));
      }
      int sl = (cc*4+q) ^ (row&7);
      *(s16x8*)(xs + row*C_ + sl*8) = o8;
    }
  }
}

__device__ __forceinline__ void load_afr(s16x8 afr[2][4], const float* __restrict__ W, int wid, int lm, int lh){
  #pragma unroll
  for (int t = 0; t < 2; t++){
    int T = wid*2 + t;
    #pragma unroll
    for (int ks = 0; ks < 4; ks++){
      const float* wr = W + (size_t)(T*16 + lm)*C_ + ks*32 + lh*8;
      float4 w0 = *(const float4*)wr;
      float4 w1 = *(const float4*)(wr+4);
      s16x8 a;
      a[0]=f2b(w0.x); a[1]=f2b(w0.y); a[2]=f2b(w0.z); a[3]=f2b(w0.w);
      a[4]=f2b(w1.x); a[5]=f2b(w1.y); a[6]=f2b(w1.z); a[7]=f2b(w1.w);
      afr[t][ks] = a;
    }
  }
}

__device__ __forceinline__ void mfma_tile(f32x4 acc[2][4], const s16x8 afr[2][4],
    const ushort* xs, const float* __restrict__ bias, int wid, int lm, int lh)
{
  #pragma unroll
  for (int t = 0; t < 2; t++){
    f32x4 bs = *(const f32x4*)(bias + (wid*2+t)*16 + lh*4);
    #pragma unroll
    for (int ps = 0; ps < 4; ps++) acc[t][ps] = bs;
  }
  #pragma unroll
  for (int ps = 0; ps < 4; ps++){
    int row = ps*16 + lm;
    s16x8 bf[4];
    #pragma unroll
    for (int ks = 0; ks < 4; ks++){
      int sl = (ks*4+lh) ^ (row&7);
      bf[ks] = *(const s16x8*)(xs + row*C_ + sl*8);
    }
    #pragma unroll
    for (int ks = 0; ks < 4; ks++){
      #pragma unroll
      for (int t = 0; t < 2; t++)
        acc[t][ps] = __builtin_amdgcn_mfma_f32_16x16x32_bf16(afr[t][ks], bf[ks], acc[t][ps], 0,0,0);
    }
  }
}

template<int STAGE, int EPI>
__device__ __forceinline__ void mgemm_body(ushort* xs, float* sblk,
    const ushort* __restrict__ Xb, const float* __restrict__ W, const float* __restrict__ bias,
    const float* __restrict__ prm, const float4* __restrict__ pt4, const int* __restrict__ idx,
    const ushort* __restrict__ Aq, const ushort* __restrict__ Ak,
    void* __restrict__ Y, float* __restrict__ gsum, float* __restrict__ gssq, int bsh, int bx)
{
  int tid = threadIdx.x;
  int l = tid & 63, wid = tid >> 6;
  int lm = l & 15, lh = l >> 4;
  int p0 = bx * 64;
  int b = p0 >> bsh;

  if (tid < 16) sblk[tid] = 0.f;

  s16x8 afr[2][4];
  load_afr(afr, W, wid, lm, lh);
  stage_x<STAGE>(xs, Xb, prm, pt4, idx, p0, b);
  __syncthreads();

  f32x4 acc[2][4];
  mfma_tile(acc, afr, xs, bias, wid, lm, lh);

  // ---- epilogue ----
  float gs[2] = {0.f,0.f}, gq[2] = {0.f,0.f};
  #pragma unroll
  for (int t = 0; t < 2; t++){
    int T = wid*2 + t;
    int o0 = T*16 + lh*4;
    #pragma unroll
    for (int ps = 0; ps < 4; ps++){
      int p = p0 + ps*16 + lm;
      if constexpr (EPI == EP_PM){
        s16x4 r4;
        #pragma unroll
        for (int r = 0; r < 4; r++) r4[r] = f2b(acc[t][ps][r]);
        *(s16x4*)((ushort*)Y + (size_t)p*C_ + o0) = r4;
      } else if constexpr (EPI == EP_QKS){
        int ng = p >> 4;
        int j = idx[p];
        s16x4 aq4 = *(const s16x4*)(Aq + (size_t)ng*C_ + o0);
        s16x4 ak4 = *(const s16x4*)(Ak + ((size_t)(b<<13)+j)*C_ + o0);
        s16x4 r4;
        #pragma unroll
        for (int r = 0; r < 4; r++){
          float v = acc[t][ps][r] + b2f(aq4[r]) - b2f(ak4[r]);
          r4[r] = f2b(v);
          gs[t] += v; gq[t] += v*v;
        }
        *(s16x4*)((ushort*)Y + (size_t)p*C_ + o0) = r4;
      } else { // EP_F32CM
        float* yf = (float*)Y;
        #pragma unroll
        for (int r = 0; r < 4; r++){
          float v = acc[t][ps][r];
          yf[(size_t)(o0+r)*BN_ + p] = v;
          gs[t] += v; gq[t] += v*v;
        }
      }
    }
  }

  if constexpr (EPI == EP_QKS || EPI == EP_F32CM){
    #pragma unroll
    for (int t = 0; t < 2; t++){
      float s = gs[t], q = gq[t];
      #pragma unroll
      for (int mk = 32; mk; mk >>= 1){ s += __shfl_xor(s, mk, 64); q += __shfl_xor(q, mk, 64); }
      if (l == 0){
        int T = wid*2 + t;
        atomicAdd(&sblk[T], s); atomicAdd(&sblk[8+T], q);
      }
    }
    __syncthreads();
    if (tid < 8){
      atomicAdd(&gsum[b*G_ + tid], sblk[tid]);
      atomicAdd(&gssq[b*G_ + tid], sblk[8+tid]);
    }
  }
}

template<int STAGE, int EPI>
__global__ __launch_bounds__(256) void mgemm_kernel(
    const ushort* __restrict__ Xb, const float* __restrict__ W, const float* __restrict__ bias,
    const float* __restrict__ prm, const float4* __restrict__ pt4, const int* __restrict__ idx,
    const ushort* __restrict__ Aq, const ushort* __restrict__ Ak,
    void* __restrict__ Y, float* __restrict__ gsum, float* __restrict__ gssq, int bsh)
{
  __shared__ ushort xs[64*128];
  __shared__ float sblk[16];
  mgemm_body<STAGE,EPI>(xs, sblk, Xb, W, bias, prm, pt4, idx, Aq, Ak, Y, gsum, gssq, bsh, blockIdx.x);
}

// v / Aq / Ak in one launch (gridDim.y = 3)
__global__ __launch_bounds__(256) void qkv_kernel(const ushort* __restrict__ nfb,
    const float* __restrict__ Wv, const float* __restrict__ bv,
    const float* __restrict__ Wqa, const float* __restrict__ bqa,
    const float* __restrict__ Wka, const float* __restrict__ bka,
    ushort* __restrict__ vb, ushort* __restrict__ Aqb, ushort* __restrict__ Akb)
{
  __shared__ ushort xs[64*128];
  __shared__ float sblk[16];
  if (blockIdx.y == 0)
    mgemm_body<ST_COPY,EP_PM>(xs, sblk, nfb, Wv, bv, nullptr, nullptr, nullptr, nullptr, nullptr, vb, nullptr, nullptr, 13, blockIdx.x);
  else if (blockIdx.y == 1)
    mgemm_body<ST_COPY,EP_PM>(xs, sblk, nfb, Wqa, bqa, nullptr, nullptr, nullptr, nullptr, nullptr, Aqb, nullptr, nullptr, 13, blockIdx.x);
  else
    mgemm_body<ST_COPY,EP_PM>(xs, sblk, nfb, Wka, bka, nullptr, nullptr, nullptr, nullptr, nullptr, Akb, nullptr, nullptr, 13, blockIdx.x);
}

// ---------------- fused: GN(att1) -> W_att2 GEMM -> softmax(k) -> PV + residual ----------------
__global__ __launch_bounds__(256) void fatt_kernel(const ushort* __restrict__ Xb /*att1 PM*/,
    const float* __restrict__ W /*W_att2*/, const float* __restrict__ bias /*b_att2*/,
    const float* __restrict__ prm /*attPrm*/, const int* __restrict__ idx,
    const ushort* __restrict__ vb, const ushort* __restrict__ nfb, ushort* __restrict__ outb)
{
  __shared__ ushort xs[64*128];
  int tid = threadIdx.x;
  int l = tid & 63, wid = tid >> 6;
  int lm = l & 15, lh = l >> 4;
  int p0 = blockIdx.x * 64;
  int b = p0 >> 17;

  // prefetch V gathers first (latency overlaps staging global loads + transform + MFMA)
  s16x4 vpre[2][4];
  #pragma unroll
  for (int ps = 0; ps < 4; ps++){
    int p = p0 + ps*16 + lm;
    int j = idx[p];
    const ushort* vr = vb + ((size_t)(b<<13)+j)*C_ + lh*4;
    #pragma unroll
    for (int t = 0; t < 2; t++)
      vpre[t][ps] = *(const s16x4*)(vr + (wid*2+t)*16);
  }

  s16x8 afr[2][4];
  load_afr(afr, W, wid, lm, lh);
  stage_x<ST_GN>(xs, Xb, prm, nullptr, nullptr, p0, b);
  __syncthreads();

  f32x4 acc[2][4];
  mfma_tile(acc, afr, xs, bias, wid, lm, lh);

  // softmax over k (lm) + PV + residual — DPP row reductions (VALU-only)
  #pragma unroll
  for (int t = 0; t < 2; t++){
    int o0 = (wid*2+t)*16 + lh*4;
    #pragma unroll
    for (int ps = 0; ps < 4; ps++){
      s16x4 v4 = vpre[t][ps];
      f32x4 e, pv;
      #pragma unroll
      for (int r = 0; r < 4; r++){
        float ev = __expf(acc[t][ps][r]);
        e[r] = ev;
        pv[r] = ev * b2f(v4[r]);
      }
      #pragma unroll
      for (int r = 0; r < 4; r++){
        e[r]  = red16(e[r]);
        pv[r] = red16(pv[r]);
      }
      if (lm == 0){
        int n = (p0 + ps*16) >> 4;
        s16x4 n4 = *(const s16x4*)(nfb + (size_t)n*C_ + o0);
        s16x4 o4;
        #pragma unroll
        for (int r = 0; r < 4; r++) o4[r] = f2b(pv[r]/e[r] + b2f(n4[r]));
        *(s16x4*)(outb + (size_t)n*C_ + o0) = o4;
      }
    }
  }
}

// ---------------- final: inline post-finalize + GN + leaky (out1 col-major [C][BN]) ----------------
__global__ __launch_bounds__(256) void final_kernel(const float* __restrict__ out1,
    const float* __restrict__ gsum, const float* __restrict__ gssq,
    const float* __restrict__ g, const float* __restrict__ be, float* __restrict__ out){
  int e = blockIdx.x*256 + threadIdx.x;
  int b = e >> 20;
  int c = (e >> 13) & (C_-1);
  int n = e & (N_-1);
  int gi = b*G_ + (c >> 4);
  const float invcnt = 1.0f/(float)(16*N_);
  float m = gsum[gi]*invcnt;
  float var = gssq[gi]*invcnt - m*m;
  var = fmaxf(var, 0.f);
  float r = rsqrtf(var + EPSV);
  float v = (out1[(size_t)c*BN_ + b*N_ + n] - m) * r;
  v = v*g[c] + be[c];
  out[e] = leakyf(v);
}

extern "C" void kernel_launch(void* const* d_in, const int* in_sizes, int n_in,
                              void* d_out, int out_size, void* d_ws, size_t ws_size,
                              hipStream_t stream) {
  const float* xyz    = (const float*)d_in[0];
  const float* feat   = (const float*)d_in[1];
  const float* W_pre  = (const float*)d_in[2];
  const float* b_pre  = (const float*)d_in[3];
  const float* W_pos1 = (const float*)d_in[4];
  const float* b_pos1 = (const float*)d_in[5];
  const float* g_pos1 = (const float*)d_in[6];
  const float* be_pos1= (const float*)d_in[7];
  const float* W_pos2 = (const float*)d_in[8];
  const float* b_pos2 = (const float*)d_in[9];
  const float* W_q    = (const float*)d_in[10];
  const float* b_q    = (const float*)d_in[11];
  const float* W_k    = (const float*)d_in[12];
  const float* b_k    = (const float*)d_in[13];
  const float* W_v    = (const float*)d_in[14];
  const float* b_v    = (const float*)d_in[15];
  const float* W_att1 = (const float*)d_in[16];
  const float* b_att1 = (const float*)d_in[17];
  const float* g_att1 = (const float*)d_in[18];
  const float* be_att1= (const float*)d_in[19];
  const float* W_att2 = (const float*)d_in[20];
  const float* b_att2 = (const float*)d_in[21];
  const float* W_post = (const float*)d_in[22];
  const float* b_post = (const float*)d_in[23];
  const float* g_post = (const float*)d_in[24];
  const float* be_post= (const float*)d_in[25];

  char* w = (char*)d_ws;
  float4* pt4 = (float4*)w;            w += sizeof(float4)*BN_;
  int* idx = (int*)w;                  w += sizeof(int)*BNK_;
  ushort* fb   = (ushort*)w;           w += (size_t)2*BN_*C_;
  ushort* nfb  = (ushort*)w;           w += (size_t)2*BN_*C_;
  ushort* vb   = (ushort*)w;           w += (size_t)2*BN_*C_;
  ushort* Aqb  = (ushort*)w;           w += (size_t)2*BN_*C_;
  ushort* Akb  = (ushort*)w;           w += (size_t)2*BN_*C_;
  ushort* outb = (ushort*)w;           w += (size_t)2*BN_*C_;
  float* out1  = (float*)w;            w += (size_t)4*BN_*C_;
  ushort* bufA = (ushort*)w;           w += (size_t)2*BNK_*C_;           // att1 PM
  float* Wf    = (float*)w;            w += sizeof(float)*C_*C_;
  float* Wqa   = (float*)w;            w += sizeof(float)*C_*C_;
  float* Wka   = (float*)w;            w += sizeof(float)*C_*C_;
  float* bG1   = (float*)w;            w += 512;
  float* bqa   = (float*)w;            w += 512;
  float* bka   = (float*)w;            w += 512;
  float* posPrm= (float*)w;            w += sizeof(float)*1024;
  float* attPrm= (float*)w;            w += sizeof(float)*512;
  float* stats = (float*)w;            w += 1024;
  int* cellCnt = (int*)w;              w += sizeof(int)*2*NC_;
  int* cellStart=(int*)w;              w += sizeof(int)*(2*NC_+1);
  int* cellCur = (int*)w;              w += sizeof(int)*2*NC_;
  float4* spts = (float4*)w;           w += sizeof(float4)*BN_;
  int* sidx    = (int*)w;              w += sizeof(int)*BN_;

  float* posMom = stats + 0;                     // 2*9 floats
  float* att_sum = stats + 64, *att_ssq = stats + 80;
  float* post_sum= stats +128, *post_ssq= stats +144;

  hipMemsetAsync(stats, 0, 1024, stream);
  hipMemsetAsync(cellCnt, 0, sizeof(int)*2*NC_, stream);

  pack_featb_kernel<<<BN_/256, 256, 0, stream>>>(xyz, feat, pt4, fb, cellCnt);
  scan_kernel<<<1, 1024, 0, stream>>>(cellCnt, cellStart, cellCur);
  scatter_kernel<<<BN_/256, 256, 0, stream>>>(pt4, cellCur, spts, sidx);
  knn_kernel<<<BN_/8, 512, 0, stream>>>(pt4, spts, sidx, cellStart, idx);

  // fused weights / biases (one launch)
  setup_kernel<<<193, 256, 0, stream>>>(W_att1, W_pos2, W_q, W_k, b_pos2, b_att1, b_q, b_k,
      Wf, Wqa, Wka, bG1, bqa, bka);

  // nf = W_pre*feat + b
  mgemm_kernel<ST_COPY,EP_PM><<<BN_/64, 256, 0, stream>>>(fb, W_pre, b_pre, nullptr, nullptr, nullptr,
      nullptr, nullptr, nfb, nullptr, nullptr, 13);
  // v, Aq, Ak (one launch)
  qkv_kernel<<<dim3(BN_/64, 3), 256, 0, stream>>>(nfb, W_v, b_v, Wqa, bqa, Wka, bka, vb, Aqb, Akb);

  // pos GN stats via moments -> folded params
  posmom_kernel<<<BNK_/256, 256, 0, stream>>>(pt4, idx, posMom);
  posfin_kernel<<<1, 256, 0, stream>>>(posMom, W_pos1, b_pos1, g_pos1, be_pos1, posPrm);

  // G1: att1 = Wf*posn + bG1 + Aq[n] - Ak[j]  (+ stats)  -> bufA
  mgemm_kernel<ST_POS,EP_QKS><<<BNK_/64, 256, 0, stream>>>(nullptr, Wf, bG1, posPrm, pt4, idx,
      Aqb, Akb, bufA, att_sum, att_ssq, 17);
  attfin_kernel<<<1, 256, 0, stream>>>(att_sum, att_ssq, g_att1, be_att1, attPrm, 1.0f/(float)(16.0*NK_));

  // fused G2 + softmax + PV + residual
  fatt_kernel<<<BNK_/64, 256, 0, stream>>>(bufA, W_att2, b_att2, attPrm, idx, vb, nfb, outb);

  // post conv + stats (f32 col-major)
  mgemm_kernel<ST_COPY,EP_F32CM><<<BN_/64, 256, 0, stream>>>(outb, W_post, b_post, nullptr, nullptr, nullptr,
      nullptr, nullptr, out1, post_sum, post_ssq, 13);
  final_kernel<<<(B_*CN_)/256, 256, 0, stream>>>(out1, post_sum, post_ssq, g_post, be_post, (float*)d_out);
}

// Round 16
// 335.846 us; speedup vs baseline: 1.0593x; 1.0046x over previous
//
#include <hip/hip_runtime.h>
#include <hip/hip_bf16.h>
#include <float.h>

#define B_ 2
#define N_ 8192
#define C_ 128
#define K_ 16
#define G_ 8
#define NK_ (N_*K_)     // 131072
#define BN_ (B_*N_)     // 16384
#define BNK_ (B_*NK_)   // 262144
#define CN_ (C_*N_)
#define NEG 0.1f
#define EPSV 1e-5f

// KNN grid: 24^3 cells, h=0.5, box [-6,6]
#define GR_ 24
#define NC_ (GR_*GR_*GR_)    // 13824 cells per batch
#define GLOF -6.0f
#define GHF 0.5f
#define KNN_MARGIN 2e-4f
#define EMPTY_KEY 0x7FEFFFFFFFFFFFFFull

typedef __attribute__((ext_vector_type(4))) float f32x4;
typedef __attribute__((ext_vector_type(8))) short s16x8;
typedef __attribute__((ext_vector_type(4))) short s16x4;

__device__ __forceinline__ float leakyf(float x){ return x >= 0.f ? x : NEG*x; }
__device__ __forceinline__ short f2b(float x){
  union { __hip_bfloat16 b; short s; } u; u.b = __float2bfloat16(x); return u.s;
}
__device__ __forceinline__ float b2f(short s){
  union { __hip_bfloat16 b; short s; } u; u.s = s; return __bfloat162float(u.b);
}

// row_shr:1 within 16-lane rows (list lives in lanes 0..15 -> row-local)
__device__ __forceinline__ int dpp_shr1_i(int x){
  return __builtin_amdgcn_update_dpp(x, x, 0x111, 0xF, 0xF, false);
}
__device__ __forceinline__ unsigned long long dpp_shr1_u64(unsigned long long x){
  union { unsigned long long q; int i[2]; } u; u.q = x;
  u.i[0] = dpp_shr1_i(u.i[0]);
  u.i[1] = dpp_shr1_i(u.i[1]);
  return u.q;
}
__device__ __forceinline__ unsigned long long readlane_u64(unsigned long long x, int l){
  union { unsigned long long q; int i[2]; } u; u.q = x;
  union { unsigned long long q; int i[2]; } r;
  r.i[0] = __builtin_amdgcn_readlane(u.i[0], l);
  r.i[1] = __builtin_amdgcn_readlane(u.i[1], l);
  return r.q;
}
// sort key: d2 (clamped >=0) bits, low 13 mantissa bits replaced by idx.
__device__ __forceinline__ unsigned long long d2key(double d2, int idx){
  d2 = fmax(d2, 0.0);
  union { double d; unsigned long long q; } u; u.d = d2;
  return (u.q & ~0x1FFFull) | (unsigned long long)idx;
}
__device__ __forceinline__ double key_upper_d2(unsigned long long k){
  union { unsigned long long q; double d; } u; u.q = k | 0x1FFFull;   // round up: conservative
  return u.d;
}
__device__ __forceinline__ int cell1(float x){
  int c = (int)floorf((x - GLOF)*(1.0f/GHF));
  return min(max(c, 0), GR_-1);
}

// DPP float move (ctrl as template constant; all rows/banks, bound_ctrl=1)
template<int CTRL>
__device__ __forceinline__ float dppf(float x){
  union { float f; int i; } u; u.f = x;
  u.i = __builtin_amdgcn_update_dpp(0, u.i, CTRL, 0xF, 0xF, true);
  return u.f;
}
// 16-lane row sum, identical pairing to xor1/2/4/8 butterfly (bit-identical result)
__device__ __forceinline__ float red16(float x){
  x += dppf<0xB1>(x);    // quad_perm [1,0,3,2] : xor 1
  x += dppf<0x4E>(x);    // quad_perm [2,3,0,1] : xor 2
  x += dppf<0x141>(x);   // row_half_mirror     : xor 4
  x += dppf<0x140>(x);   // row_mirror          : xor 8
  return x;
}

// ---------------- pack xyz -> float4 (w=|p|^2 fp32) + feat -> bf16 PM + cell histogram ----------------
__global__ __launch_bounds__(256) void pack_featb_kernel(const float* __restrict__ xyz,
    const float* __restrict__ feat, float4* __restrict__ pt4, ushort* __restrict__ fb,
    int* __restrict__ cellCnt){
  int e = blockIdx.x*256 + threadIdx.x;
  int b = e >> 13, n = e & (N_-1);
  const float* xb = xyz + b*3*N_;
  float x = xb[n], y = xb[N_+n], z = xb[2*N_+n];
  pt4[e] = make_float4(x, y, z, x*x + y*y + z*z);
  atomicAdd(&cellCnt[b*NC_ + (cell1(z)*GR_ + cell1(y))*GR_ + cell1(x)], 1);
  const float* xin = feat + b*CN_ + n;
  #pragma unroll
  for (int c0 = 0; c0 < C_; c0 += 8){
    s16x8 o8;
    #pragma unroll
    for (int i = 0; i < 8; i++) o8[i] = f2b(xin[(size_t)(c0+i)*N_]);
    *(s16x8*)(fb + (size_t)e*C_ + c0) = o8;
  }
}

// ---------------- exclusive prefix scan over 2*NC_ = 27648 cells (single block, 27/thread) ----------------
__global__ __launch_bounds__(1024) void scan_kernel(const int* __restrict__ cnt,
    int* __restrict__ cellStart, int* __restrict__ cellCur){
  __shared__ int bs[1024];
  int t = threadIdx.x;
  int base = t*27;
  int s = 0;
  for (int i = 0; i < 27; i++) s += cnt[base+i];
  bs[t] = s;
  __syncthreads();
  for (int off = 1; off < 1024; off <<= 1){
    int v = (t >= off) ? bs[t-off] : 0;
    __syncthreads();
    bs[t] += v;
    __syncthreads();
  }
  int run = (t == 0) ? 0 : bs[t-1];
  for (int i = 0; i < 27; i++){
    cellStart[base+i] = run;
    cellCur[base+i]  = run;
    run += cnt[base+i];
  }
  if (t == 1023) cellStart[2*NC_] = BN_;
}

// ---------------- scatter points into cell-sorted order ----------------
__global__ __launch_bounds__(256) void scatter_kernel(const float4* __restrict__ pt4,
    int* __restrict__ cellCur, float4* __restrict__ spts, int* __restrict__ sidx){
  int e = blockIdx.x*256 + threadIdx.x;
  int b = e >> 13;
  float4 p = pt4[e];
  int cid = b*NC_ + (cell1(p.z)*GR_ + cell1(p.y))*GR_ + cell1(p.x);
  int slot = atomicAdd(&cellCur[cid], 1);
  spts[slot] = p;
  sidx[slot] = e & (N_-1);
}

// ---------------- KNN hybrid: ring-1 grid pass; 2x-unrolled brute fallback ----------------
__global__ __launch_bounds__(512) void knn_kernel(const float4* __restrict__ pt4,
    const float4* __restrict__ spts, const int* __restrict__ sidx,
    const int* __restrict__ cellStart, int* __restrict__ idxo){
  int lane = threadIdx.x & 63, wid = threadIdx.x >> 6;
  int qg = blockIdx.x*8 + wid;           // sorted slot
  int b = qg >> 13;
  float4 qp = spts[qg];
  int nq = sidx[qg];                     // original point index within batch
  double qx = qp.x, qy = qp.y, qz = qp.z;
  double qsq = qx*qx + qy*qy + qz*qz;
  float qx2 = -2.f*qp.x, qy2 = -2.f*qp.y, qz2 = -2.f*qp.z;
  unsigned long long mykey = EMPTY_KEY;  // lanes 0..15: sorted top-16 keys
  float cmpv = FLT_MAX;
  int ci = cell1(qp.x), cj = cell1(qp.y), ck = cell1(qp.z);

  auto process = [&](unsigned long long m, unsigned long long keyv){
    while (m){
      int src = __ffsll(m) - 1; m &= m - 1;
      unsigned long long kn = readlane_u64(keyv, src);
      bool less = kn < mykey;
      unsigned long long bm = __ballot(less) & 0xFFFFull;
      if (bm){
        int pos = __ffsll(bm) - 1;
        unsigned long long pk = dpp_shr1_u64(mykey);
        if (lane < 16){
          if (lane > pos) mykey = pk;
          else if (lane == pos) mykey = kn;
        }
      }
    }
  };

  auto do_range = [&](int cid0, int cid1){
    int s = cellStart[cid0], e = cellStart[cid1+1];
    for (int off = s; off < e; off += 64){
      int t = off + lane;
      bool valid = t < e;
      float4 pp = make_float4(0.f, 0.f, 0.f, 3.0e38f);
      int oi = 0;
      if (valid){ pp = spts[t]; oi = sidx[t]; }
      float f = fmaf(pp.x, qx2, fmaf(pp.y, qy2, fmaf(pp.z, qz2, pp.w)));
      unsigned long long m = __ballot(valid && (f < cmpv));
      if (m){
        double px = pp.x, py = pp.y, pz = pp.z;
        double psq = px*px + py*py + pz*pz;
        double dot = qx*px + qy*py + qz*pz;
        process(m, d2key(qsq + psq - 2.0*dot, oi));
        cmpv = fminf(cmpv, (float)(key_upper_d2(readlane_u64(mykey, 15)) - qsq) + KNN_MARGIN);
      }
    }
  };

  // phase 1: ring 0+1 as 9 contiguous x-runs; own row first for fast threshold convergence
  int x0 = max(ci-1, 0), x1 = min(ci+1, GR_-1);
  int cbase = b*NC_;
  do_range(cbase + (ck*GR_ + cj)*GR_ + x0, cbase + (ck*GR_ + cj)*GR_ + x1);
  for (int dz = -1; dz <= 1; dz++){
    int z = ck + dz; if (z < 0 || z >= GR_) continue;
    for (int dy = -1; dy <= 1; dy++){
      int y = cj + dy; if (y < 0 || y >= GR_) continue;
      if ((dy | dz) == 0) continue;
      do_range(cbase + (z*GR_ + y)*GR_ + x0, cbase + (z*GR_ + y)*GR_ + x1);
    }
  }

  // exact coverage bound: points outside ring-1 are >= h away (cells exact in fp32)
  double thr_up = key_upper_d2(readlane_u64(mykey, 15));
  if (thr_up > (double)GHF*(double)GHF){
    // phase 2: brute-force over original order (2x unrolled); reset list, keep filter
    mykey = EMPTY_KEY;
    const float4* pts = pt4 + (b << 13);
    for (int t0 = 0; t0 < N_; t0 += 128){
      float4 pA = pts[t0 + lane];
      float4 pB = pts[t0 + 64 + lane];
      float fA = fmaf(pA.x, qx2, fmaf(pA.y, qy2, fmaf(pA.z, qz2, pA.w)));
      float fB = fmaf(pB.x, qx2, fmaf(pB.y, qy2, fmaf(pB.z, qz2, pB.w)));
      unsigned long long mA = __ballot(fA < cmpv);
      unsigned long long mB = __ballot(fB < cmpv);
      if (mA | mB){
        if (mA){
          double px = pA.x, py = pA.y, pz = pA.z;
          double psq = px*px + py*py + pz*pz;
          double dot = qx*px + qy*py + qz*pz;
          process(mA, d2key(qsq + psq - 2.0*dot, t0 + lane));
        }
        if (mB){
          double px = pB.x, py = pB.y, pz = pB.z;
          double psq = px*px + py*py + pz*pz;
          double dot = qx*px + qy*py + qz*pz;
          process(mB, d2key(qsq + psq - 2.0*dot, t0 + 64 + lane));
        }
        cmpv = fminf(cmpv, (float)(key_upper_d2(readlane_u64(mykey, 15)) - qsq) + KNN_MARGIN);
      }
    }
  }
  if (lane < 16) idxo[((size_t)(b<<13) + nq)*K_ + lane] = (int)(mykey & 0x1FFFull);
}

// ---------------- setup: fused weights (3 x 128^3) + fused biases ----------------
__global__ __launch_bounds__(256) void setup_kernel(const float* __restrict__ W_att1,
    const float* __restrict__ W_pos2, const float* __restrict__ W_q, const float* __restrict__ W_k,
    const float* __restrict__ b_pos2, const float* __restrict__ b_att1,
    const float* __restrict__ b_q, const float* __restrict__ b_k,
    float* __restrict__ Wf, float* __restrict__ Wqa, float* __restrict__ Wka,
    float* __restrict__ bG1, float* __restrict__ bqa, float* __restrict__ bka){
  int bx = blockIdx.x;
  if (bx < 192){
    int which = bx >> 6;
    const float* Bm = which==0 ? W_pos2 : (which==1 ? W_q : W_k);
    float* Cm = which==0 ? Wf : (which==1 ? Wqa : Wka);
    int e = (bx & 63)*256 + threadIdx.x;
    int o = e >> 7, c = e & 127;
    float s = 0.f;
    #pragma unroll 8
    for (int m = 0; m < 128; m++) s += W_att1[o*128+m]*Bm[m*128+c];
    Cm[e] = s;
  } else {
    for (int t = threadIdx.x; t < 384; t += 256){
      int which = t >> 7, o = t & 127;
      const float* v = which==0 ? b_pos2 : (which==1 ? b_q : b_k);
      float* out = which==0 ? bG1 : (which==1 ? bqa : bka);
      float s = which==0 ? b_att1[o] : 0.f;
      for (int m = 0; m < 128; m++) s += W_att1[o*128+m]*v[m];
      out[o] = s;
    }
  }
}

// ---------------- pos moments: per-batch [R(3), S_diag(3), S_off(3)] over rel = pj - pn ----------------
__global__ __launch_bounds__(256) void posmom_kernel(const float4* __restrict__ pt4,
    const int* __restrict__ idx, float* __restrict__ mom){
  __shared__ float ls[9];
  if (threadIdx.x < 9) ls[threadIdx.x] = 0.f;
  __syncthreads();
  int p = blockIdx.x*256 + threadIdx.x;
  int b = p >> 17;
  int n = p >> 4;
  int j = idx[p];
  float4 pj = pt4[(b<<13) + j], pn = pt4[n];
  float rx = pj.x - pn.x, ry = pj.y - pn.y, rz = pj.z - pn.z;
  float m9[9] = { rx, ry, rz, rx*rx, ry*ry, rz*rz, rx*ry, rx*rz, ry*rz };
  #pragma unroll
  for (int i = 0; i < 9; i++){
    float s = m9[i];
    #pragma unroll
    for (int mk = 32; mk; mk >>= 1) s += __shfl_xor(s, mk, 64);
    if ((threadIdx.x & 63) == 0) atomicAdd(&ls[i], s);
  }
  __syncthreads();
  if (threadIdx.x < 9) atomicAdd(&mom[b*9 + threadIdx.x], ls[threadIdx.x]);
}

// ---------------- pos finalize from moments + folded GN params (float4: sx,sy,sz,so) ----------------
__global__ void posfin_kernel(const float* __restrict__ mom,
    const float* __restrict__ W1, const float* __restrict__ b1,
    const float* __restrict__ g1, const float* __restrict__ be1, float* __restrict__ prm){
  int i = threadIdx.x;           // 256: b = i>>7, c = i&127
  int b = i >> 7, c = i & 127;
  const float* M = mom + b*9;
  float wx = W1[3*c], wy = W1[3*c+1], wz = W1[3*c+2], bb = b1[c];
  const float cnt = (float)NK_;
  float wr = wx*M[0] + wy*M[1] + wz*M[2];
  float s_c = wr + bb*cnt;
  float q_c = wx*wx*M[3] + wy*wy*M[4] + wz*wz*M[5]
            + 2.f*(wx*wy*M[6] + wx*wz*M[7] + wy*wz*M[8])
            + 2.f*bb*wr + bb*bb*cnt;
  #pragma unroll
  for (int mk = 1; mk < 16; mk <<= 1){
    s_c += __shfl_xor(s_c, mk, 64);
    q_c += __shfl_xor(q_c, mk, 64);
  }
  const float invcnt = 1.0f/(16.0f*(float)NK_);
  float m = s_c*invcnt;
  float var = q_c*invcnt - m*m;
  var = fmaxf(var, 0.f);
  float r = rsqrtf(var + EPSV);
  float rs = r*g1[c];
  float4* p4 = (float4*)prm;
  p4[b*128 + c] = make_float4(wx*rs, wy*rs, wz*rs, (bb-m)*rs + be1[c]);
}

// ---------------- att finalize + folded scale/shift (interleaved float2: sc,sh) ----------------
__global__ void attfin_kernel(const float* __restrict__ gsum, const float* __restrict__ gssq,
    const float* __restrict__ ga, const float* __restrict__ bea, float* __restrict__ prm, float invcnt){
  __shared__ float sm[16], sr[16];
  int i = threadIdx.x;
  if (i < 16){
    float m = gsum[i]*invcnt;
    float v = gssq[i]*invcnt - m*m;
    v = fmaxf(v, 0.f);
    sm[i] = m; sr[i] = rsqrtf(v + EPSV);
  }
  __syncthreads();
  int b = i >> 7, c = i & 127, g = c >> 4;
  float sc = ga[c]*sr[b*G_+g];
  float2* p2 = (float2*)prm;
  p2[b*128 + c] = make_float2(sc, bea[c] - sm[b*G_+g]*sc);
}

// ---------------- unified MFMA GEMM body: Y[o][p] = W*X + bias, 64 pts x 128 out ----------------
#define ST_COPY 0
#define ST_GN   1
#define ST_POS  2
#define EP_PM    0
#define EP_QKS   1
#define EP_F32CM 2

template<int STAGE>
__device__ __forceinline__ void stage_x(ushort* xs,
    const ushort* __restrict__ Xb, const float* __restrict__ prm,
    const float4* __restrict__ pt4, const int* __restrict__ idx, int p0, int b)
{
  int tid = threadIdx.x;
  int row = tid & 63, cc = tid >> 6;
  if constexpr (STAGE == ST_COPY){
    const ushort* src = Xb + (size_t)(p0+row)*C_ + cc*32;
    #pragma unroll
    for (int q = 0; q < 4; q++){
      s16x8 v8 = *(const s16x8*)(src + q*8);
      int sl = (cc*4+q) ^ (row&7);
      *(s16x8*)(xs + row*C_ + sl*8) = v8;
    }
  } else if constexpr (STAGE == ST_GN){
    const ushort* src = Xb + (size_t)(p0+row)*C_ + cc*32;
    const float2* pr = (const float2*)prm + b*128;
    #pragma unroll
    for (int q = 0; q < 4; q++){
      s16x8 v8 = *(const s16x8*)(src + q*8);
      s16x8 o8;
      #pragma unroll
      for (int i = 0; i < 8; i++){
        int c = cc*32 + q*8 + i;
        float2 s2 = pr[c];
        o8[i] = f2b(leakyf(b2f(v8[i])*s2.x + s2.y));
      }
      int sl = (cc*4+q) ^ (row&7);
      *(s16x8*)(xs + row*C_ + sl*8) = o8;
    }
  } else { // ST_POS
    int p = p0 + row;
    int ng = p >> 4;
    int j = idx[p];
    float4 pj = pt4[(b<<13) + j], pn = pt4[ng];
    float rx = pj.x - pn.x, ry = pj.y - pn.y, rz = pj.z - pn.z;
    const float4* pr = (const float4*)prm + b*128;
    #pragma unroll
    for (int q = 0; q < 4; q++){
      s16x8 o8;
      #pragma unroll
      for (int i = 0; i < 8; i++){
        int c = cc*32 + q*8 + i;
        float4 s4 = pr[c];
        o8[i] = f2b(leakyf(fmaf(s4.x, rx, fmaf(s4.y, ry, fmaf(s4.z, rz, s4.w)))));
      }
      int sl = (cc*4+q) ^ (row&7);
      *(s16x8*)(xs + row*C_ + sl*8) = o8;
    }
  }
}

__device__ __forceinline__ void load_afr(s16x8 afr[2][4], const float* __restrict__ W, int wid, int lm, int lh){
  #pragma unroll
  for (int t = 0; t < 2; t++){
    int T = wid*2 + t;
    #pragma unroll
    for (int ks = 0; ks < 4; ks++){
      const float* wr = W + (size_t)(T*16 + lm)*C_ + ks*32 + lh*8;
      float4 w0 = *(const float4*)wr;
      float4 w1 = *(const float4*)(wr+4);
      s16x8 a;
      a[0]=f2b(w0.x); a[1]=f2b(w0.y); a[2]=f2b(w0.z); a[3]=f2b(w0.w);
      a[4]=f2b(w1.x); a[5]=f2b(w1.y); a[6]=f2b(w1.z); a[7]=f2b(w1.w);
      afr[t][ks] = a;
    }
  }
}

__device__ __forceinline__ void mfma_tile(f32x4 acc[2][4], const s16x8 afr[2][4],
    const ushort* xs, const float* __restrict__ bias, int wid, int lm, int lh)
{
  #pragma unroll
  for (int t = 0; t < 2; t++){
    f32x4 bs = *(const f32x4*)(bias + (wid*2+t)*16 + lh*4);
    #pragma unroll
    for (int ps = 0; ps < 4; ps++) acc[t][ps] = bs;
  }
  #pragma unroll
  for (int ps = 0; ps < 4; ps++){
    int row = ps*16 + lm;
    s16x8 bf[4];
    #pragma unroll
    for (int ks = 0; ks < 4; ks++){
      int sl = (ks*4+lh) ^ (row&7);
      bf[ks] = *(const s16x8*)(xs + row*C_ + sl*8);
    }
    #pragma unroll
    for (int ks = 0; ks < 4; ks++){
      #pragma unroll
      for (int t = 0; t < 2; t++)
        acc[t][ps] = __builtin_amdgcn_mfma_f32_16x16x32_bf16(afr[t][ks], bf[ks], acc[t][ps], 0,0,0);
    }
  }
}

template<int STAGE, int EPI>
__device__ __forceinline__ void mgemm_body(ushort* xs, float* sblk,
    const ushort* __restrict__ Xb, const float* __restrict__ W, const float* __restrict__ bias,
    const float* __restrict__ prm, const float4* __restrict__ pt4, const int* __restrict__ idx,
    const ushort* __restrict__ Aq, const ushort* __restrict__ Ak,
    void* __restrict__ Y, float* __restrict__ gsum, float* __restrict__ gssq, int bsh, int bx)
{
  int tid = threadIdx.x;
  int l = tid & 63, wid = tid >> 6;
  int lm = l & 15, lh = l >> 4;
  int p0 = bx * 64;
  int b = p0 >> bsh;

  if (tid < 16) sblk[tid] = 0.f;

  s16x8 afr[2][4];
  load_afr(afr, W, wid, lm, lh);
  stage_x<STAGE>(xs, Xb, prm, pt4, idx, p0, b);
  __syncthreads();

  f32x4 acc[2][4];
  mfma_tile(acc, afr, xs, bias, wid, lm, lh);

  // ---- epilogue ----
  float gs[2] = {0.f,0.f}, gq[2] = {0.f,0.f};
  #pragma unroll
  for (int t = 0; t < 2; t++){
    int T = wid*2 + t;
    int o0 = T*16 + lh*4;
    #pragma unroll
    for (int ps = 0; ps < 4; ps++){
      int p = p0 + ps*16 + lm;
      if constexpr (EPI == EP_PM){
        s16x4 r4;
        #pragma unroll
        for (int r = 0; r < 4; r++) r4[r] = f2b(acc[t][ps][r]);
        *(s16x4*)((ushort*)Y + (size_t)p*C_ + o0) = r4;
      } else if constexpr (EPI == EP_QKS){
        int ng = p >> 4;
        int j = idx[p];
        s16x4 aq4 = *(const s16x4*)(Aq + (size_t)ng*C_ + o0);
        s16x4 ak4 = *(const s16x4*)(Ak + ((size_t)(b<<13)+j)*C_ + o0);
        s16x4 r4;
        #pragma unroll
        for (int r = 0; r < 4; r++){
          float v = acc[t][ps][r] + b2f(aq4[r]) - b2f(ak4[r]);
          r4[r] = f2b(v);
          gs[t] += v; gq[t] += v*v;
        }
        *(s16x4*)((ushort*)Y + (size_t)p*C_ + o0) = r4;
      } else { // EP_F32CM
        float* yf = (float*)Y;
        #pragma unroll
        for (int r = 0; r < 4; r++){
          float v = acc[t][ps][r];
          yf[(size_t)(o0+r)*BN_ + p] = v;
          gs[t] += v; gq[t] += v*v;
        }
      }
    }
  }

  if constexpr (EPI == EP_QKS || EPI == EP_F32CM){
    #pragma unroll
    for (int t = 0; t < 2; t++){
      float s = gs[t], q = gq[t];
      #pragma unroll
      for (int mk = 32; mk; mk >>= 1){ s += __shfl_xor(s, mk, 64); q += __shfl_xor(q, mk, 64); }
      if (l == 0){
        int T = wid*2 + t;
        atomicAdd(&sblk[T], s); atomicAdd(&sblk[8+T], q);
      }
    }
    __syncthreads();
    if (tid < 8){
      atomicAdd(&gsum[b*G_ + tid], sblk[tid]);
      atomicAdd(&gssq[b*G_ + tid], sblk[8+tid]);
    }
  }
}

template<int STAGE, int EPI>
__global__ __launch_bounds__(256) void mgemm_kernel(
    const ushort* __restrict__ Xb, const float* __restrict__ W, const float* __restrict__ bias,
    const float* __restrict__ prm, const float4* __restrict__ pt4, const int* __restrict__ idx,
    const ushort* __restrict__ Aq, const ushort* __restrict__ Ak,
    void* __restrict__ Y, float* __restrict__ gsum, float* __restrict__ gssq, int bsh)
{
  __shared__ ushort xs[64*128];
  __shared__ float sblk[16];
  mgemm_body<STAGE,EPI>(xs, sblk, Xb, W, bias, prm, pt4, idx, Aq, Ak, Y, gsum, gssq, bsh, blockIdx.x);
}

// v / Aq / Ak in one launch (gridDim.y = 3)
__global__ __launch_bounds__(256) void qkv_kernel(const ushort* __restrict__ nfb,
    const float* __restrict__ Wv, const float* __restrict__ bv,
    const float* __restrict__ Wqa, const float* __restrict__ bqa,
    const float* __restrict__ Wka, const float* __restrict__ bka,
    ushort* __restrict__ vb, ushort* __restrict__ Aqb, ushort* __restrict__ Akb)
{
  __shared__ ushort xs[64*128];
  __shared__ float sblk[16];
  if (blockIdx.y == 0)
    mgemm_body<ST_COPY,EP_PM>(xs, sblk, nfb, Wv, bv, nullptr, nullptr, nullptr, nullptr, nullptr, vb, nullptr, nullptr, 13, blockIdx.x);
  else if (blockIdx.y == 1)
    mgemm_body<ST_COPY,EP_PM>(xs, sblk, nfb, Wqa, bqa, nullptr, nullptr, nullptr, nullptr, nullptr, Aqb, nullptr, nullptr, 13, blockIdx.x);
  else
    mgemm_body<ST_COPY,EP_PM>(xs, sblk, nfb, Wka, bka, nullptr, nullptr, nullptr, nullptr, nullptr, Akb, nullptr, nullptr, 13, blockIdx.x);
}

// ---------------- fused: GN(att1) -> W_att2 GEMM -> softmax(k) -> PV + residual ----------------
// 2-tile pipeline per block: tile1 global loads issue before tile0 compute (latency overlap).
__global__ __launch_bounds__(256) void fatt_kernel(const ushort* __restrict__ Xb /*att1 PM*/,
    const float* __restrict__ W /*W_att2*/, const float* __restrict__ bias /*b_att2*/,
    const float* __restrict__ prm /*attPrm*/, const int* __restrict__ idx,
    const ushort* __restrict__ vb, const ushort* __restrict__ nfb, ushort* __restrict__ outb)
{
  __shared__ ushort xs[2][64*C_];
  int tid = threadIdx.x;
  int l = tid & 63, wid = tid >> 6;
  int lm = l & 15, lh = l >> 4;
  int row = tid & 63, cc = tid >> 6;
  int base = blockIdx.x * 128;
  int b = base >> 17;
  const float2* pr = (const float2*)prm + b*128;

  auto load_tile = [&](int p0, s16x8 L[4]){
    const ushort* src = Xb + (size_t)(p0+row)*C_ + cc*32;
    #pragma unroll
    for (int q = 0; q < 4; q++) L[q] = *(const s16x8*)(src + q*8);
  };
  auto load_vpre = [&](int p0, s16x4 vp[2][4]){
    #pragma unroll
    for (int ps = 0; ps < 4; ps++){
      int p = p0 + ps*16 + lm;
      int j = idx[p];
      const ushort* vr = vb + ((size_t)(b<<13)+j)*C_ + lh*4;
      #pragma unroll
      for (int t = 0; t < 2; t++) vp[t][ps] = *(const s16x4*)(vr + (wid*2+t)*16);
    }
  };
  auto commit_tile = [&](const s16x8 L[4], ushort* dst){
    #pragma unroll
    for (int q = 0; q < 4; q++){
      s16x8 o8;
      #pragma unroll
      for (int i = 0; i < 8; i++){
        int c = cc*32 + q*8 + i;
        float2 s2 = pr[c];
        o8[i] = f2b(leakyf(b2f(L[q][i])*s2.x + s2.y));
      }
      int sl = (cc*4+q) ^ (row&7);
      *(s16x8*)(dst + row*C_ + sl*8) = o8;
    }
  };
  auto epilogue = [&](int p0, f32x4 acc[2][4], const s16x4 vp[2][4]){
    #pragma unroll
    for (int t = 0; t < 2; t++){
      int o0 = (wid*2+t)*16 + lh*4;
      #pragma unroll
      for (int ps = 0; ps < 4; ps++){
        s16x4 v4 = vp[t][ps];
        f32x4 e, pv;
        #pragma unroll
        for (int r = 0; r < 4; r++){
          float ev = __expf(acc[t][ps][r]);
          e[r] = ev;
          pv[r] = ev * b2f(v4[r]);
        }
        #pragma unroll
        for (int r = 0; r < 4; r++){
          e[r]  = red16(e[r]);
          pv[r] = red16(pv[r]);
        }
        if (lm == 0){
          int n = (p0 + ps*16) >> 4;
          s16x4 n4 = *(const s16x4*)(nfb + (size_t)n*C_ + o0);
          s16x4 o4;
          #pragma unroll
          for (int r = 0; r < 4; r++) o4[r] = f2b(pv[r]/e[r] + b2f(n4[r]));
          *(s16x4*)(outb + (size_t)n*C_ + o0) = o4;
        }
      }
    }
  };

  s16x8 afr[2][4];
  load_afr(afr, W, wid, lm, lh);

  // tile0: load + vpre + commit
  s16x8 L0[4];
  s16x4 vp0[2][4];
  load_tile(base, L0);
  load_vpre(base, vp0);
  commit_tile(L0, xs[0]);
  // tile1: issue loads early (latency hides under tile0 compute)
  s16x8 L1[4];
  s16x4 vp1[2][4];
  load_tile(base + 64, L1);
  load_vpre(base + 64, vp1);
  __syncthreads();

  f32x4 acc[2][4];
  mfma_tile(acc, afr, xs[0], bias, wid, lm, lh);
  epilogue(base, acc, vp0);

  commit_tile(L1, xs[1]);
  __syncthreads();

  mfma_tile(acc, afr, xs[1], bias, wid, lm, lh);
  epilogue(base + 64, acc, vp1);
}

// ---------------- final: inline post-finalize + GN + leaky (out1 col-major [C][BN]) ----------------
__global__ __launch_bounds__(256) void final_kernel(const float* __restrict__ out1,
    const float* __restrict__ gsum, const float* __restrict__ gssq,
    const float* __restrict__ g, const float* __restrict__ be, float* __restrict__ out){
  int e = blockIdx.x*256 + threadIdx.x;
  int b = e >> 20;
  int c = (e >> 13) & (C_-1);
  int n = e & (N_-1);
  int gi = b*G_ + (c >> 4);
  const float invcnt = 1.0f/(float)(16*N_);
  float m = gsum[gi]*invcnt;
  float var = gssq[gi]*invcnt - m*m;
  var = fmaxf(var, 0.f);
  float r = rsqrtf(var + EPSV);
  float v = (out1[(size_t)c*BN_ + b*N_ + n] - m) * r;
  v = v*g[c] + be[c];
  out[e] = leakyf(v);
}

extern "C" void kernel_launch(void* const* d_in, const int* in_sizes, int n_in,
                              void* d_out, int out_size, void* d_ws, size_t ws_size,
                              hipStream_t stream) {
  const float* xyz    = (const float*)d_in[0];
  const float* feat   = (const float*)d_in[1];
  const float* W_pre  = (const float*)d_in[2];
  const float* b_pre  = (const float*)d_in[3];
  const float* W_pos1 = (const float*)d_in[4];
  const float* b_pos1 = (const float*)d_in[5];
  const float* g_pos1 = (const float*)d_in[6];
  const float* be_pos1= (const float*)d_in[7];
  const float* W_pos2 = (const float*)d_in[8];
  const float* b_pos2 = (const float*)d_in[9];
  const float* W_q    = (const float*)d_in[10];
  const float* b_q    = (const float*)d_in[11];
  const float* W_k    = (const float*)d_in[12];
  const float* b_k    = (const float*)d_in[13];
  const float* W_v    = (const float*)d_in[14];
  const float* b_v    = (const float*)d_in[15];
  const float* W_att1 = (const float*)d_in[16];
  const float* b_att1 = (const float*)d_in[17];
  const float* g_att1 = (const float*)d_in[18];
  const float* be_att1= (const float*)d_in[19];
  const float* W_att2 = (const float*)d_in[20];
  const float* b_att2 = (const float*)d_in[21];
  const float* W_post = (const float*)d_in[22];
  const float* b_post = (const float*)d_in[23];
  const float* g_post = (const float*)d_in[24];
  const float* be_post= (const float*)d_in[25];

  char* w = (char*)d_ws;
  float4* pt4 = (float4*)w;            w += sizeof(float4)*BN_;
  int* idx = (int*)w;                  w += sizeof(int)*BNK_;
  ushort* fb   = (ushort*)w;           w += (size_t)2*BN_*C_;
  ushort* nfb  = (ushort*)w;           w += (size_t)2*BN_*C_;
  ushort* vb   = (ushort*)w;           w += (size_t)2*BN_*C_;
  ushort* Aqb  = (ushort*)w;           w += (size_t)2*BN_*C_;
  ushort* Akb  = (ushort*)w;           w += (size_t)2*BN_*C_;
  ushort* outb = (ushort*)w;           w += (size_t)2*BN_*C_;
  float* out1  = (float*)w;            w += (size_t)4*BN_*C_;
  ushort* bufA = (ushort*)w;           w += (size_t)2*BNK_*C_;           // att1 PM
  float* Wf    = (float*)w;            w += sizeof(float)*C_*C_;
  float* Wqa   = (float*)w;            w += sizeof(float)*C_*C_;
  float* Wka   = (float*)w;            w += sizeof(float)*C_*C_;
  float* bG1   = (float*)w;            w += 512;
  float* bqa   = (float*)w;            w += 512;
  float* bka   = (float*)w;            w += 512;
  float* posPrm= (float*)w;            w += sizeof(float)*1024;
  float* attPrm= (float*)w;            w += sizeof(float)*512;
  float* stats = (float*)w;            w += 1024;
  int* cellCnt = (int*)w;              w += sizeof(int)*2*NC_;
  int* cellStart=(int*)w;              w += sizeof(int)*(2*NC_+1);
  int* cellCur = (int*)w;              w += sizeof(int)*2*NC_;
  float4* spts = (float4*)w;           w += sizeof(float4)*BN_;
  int* sidx    = (int*)w;              w += sizeof(int)*BN_;

  float* posMom = stats + 0;                     // 2*9 floats
  float* att_sum = stats + 64, *att_ssq = stats + 80;
  float* post_sum= stats +128, *post_ssq= stats +144;

  hipMemsetAsync(stats, 0, 1024, stream);
  hipMemsetAsync(cellCnt, 0, sizeof(int)*2*NC_, stream);

  pack_featb_kernel<<<BN_/256, 256, 0, stream>>>(xyz, feat, pt4, fb, cellCnt);
  scan_kernel<<<1, 1024, 0, stream>>>(cellCnt, cellStart, cellCur);
  scatter_kernel<<<BN_/256, 256, 0, stream>>>(pt4, cellCur, spts, sidx);
  knn_kernel<<<BN_/8, 512, 0, stream>>>(pt4, spts, sidx, cellStart, idx);

  // fused weights / biases (one launch)
  setup_kernel<<<193, 256, 0, stream>>>(W_att1, W_pos2, W_q, W_k, b_pos2, b_att1, b_q, b_k,
      Wf, Wqa, Wka, bG1, bqa, bka);

  // nf = W_pre*feat + b
  mgemm_kernel<ST_COPY,EP_PM><<<BN_/64, 256, 0, stream>>>(fb, W_pre, b_pre, nullptr, nullptr, nullptr,
      nullptr, nullptr, nfb, nullptr, nullptr, 13);
  // v, Aq, Ak (one launch)
  qkv_kernel<<<dim3(BN_/64, 3), 256, 0, stream>>>(nfb, W_v, b_v, Wqa, bqa, Wka, bka, vb, Aqb, Akb);

  // pos GN stats via moments -> folded params
  posmom_kernel<<<BNK_/256, 256, 0, stream>>>(pt4, idx, posMom);
  posfin_kernel<<<1, 256, 0, stream>>>(posMom, W_pos1, b_pos1, g_pos1, be_pos1, posPrm);

  // G1: att1 = Wf*posn + bG1 + Aq[n] - Ak[j]  (+ stats)  -> bufA
  mgemm_kernel<ST_POS,EP_QKS><<<BNK_/64, 256, 0, stream>>>(nullptr, Wf, bG1, posPrm, pt4, idx,
      Aqb, Akb, bufA, att_sum, att_ssq, 17);
  attfin_kernel<<<1, 256, 0, stream>>>(att_sum, att_ssq, g_att1, be_att1, attPrm, 1.0f/(float)(16.0*NK_));

  // fused G2 + softmax + PV + residual (2 tiles per block)
  fatt_kernel<<<BNK_/128, 256, 0, stream>>>(bufA, W_att2, b_att2, attPrm, idx, vb, nfb, outb);

  // post conv + stats (f32 col-major)
  mgemm_kernel<ST_COPY,EP_F32CM><<<BN_/64, 256, 0, stream>>>(outb, W_post, b_post, nullptr, nullptr, nullptr,
      nullptr, nullptr, out1, post_sum, post_ssq, 13);
  final_kernel<<<(B_*CN_)/256, 256, 0, stream>>>(out1, post_sum, post_ssq, g_post, be_post, (float*)d_out);
}

// Round 17
// 333.267 us; speedup vs baseline: 1.0675x; 1.0077x over previous
//
#include <hip/hip_runtime.h>
#include <hip/hip_bf16.h>
#include <float.h>

#define B_ 2
#define N_ 8192
#define C_ 128
#define K_ 16
#define G_ 8
#define NK_ (N_*K_)     // 131072
#define BN_ (B_*N_)     // 16384
#define BNK_ (B_*NK_)   // 262144
#define CN_ (C_*N_)
#define NEG 0.1f
#define EPSV 1e-5f

// KNN grid: 24^3 cells, h=0.5, box [-6,6]
#define GR_ 24
#define NC_ (GR_*GR_*GR_)    // 13824 cells per batch
#define GLOF -6.0f
#define GHF 0.5f
#define KNN_MARGIN 2e-4f
#define EMPTY_KEY 0x7FEFFFFFFFFFFFFFull

typedef __attribute__((ext_vector_type(4))) float f32x4;
typedef __attribute__((ext_vector_type(8))) short s16x8;
typedef __attribute__((ext_vector_type(4))) short s16x4;

__device__ __forceinline__ float leakyf(float x){ return x >= 0.f ? x : NEG*x; }
__device__ __forceinline__ short f2b(float x){
  union { __hip_bfloat16 b; short s; } u; u.b = __float2bfloat16(x); return u.s;
}
__device__ __forceinline__ float b2f(short s){
  union { __hip_bfloat16 b; short s; } u; u.s = s; return __bfloat162float(u.b);
}

// row_shr:1 within 16-lane rows (list lives in lanes 0..15 -> row-local)
__device__ __forceinline__ int dpp_shr1_i(int x){
  return __builtin_amdgcn_update_dpp(x, x, 0x111, 0xF, 0xF, false);
}
__device__ __forceinline__ unsigned long long dpp_shr1_u64(unsigned long long x){
  union { unsigned long long q; int i[2]; } u; u.q = x;
  u.i[0] = dpp_shr1_i(u.i[0]);
  u.i[1] = dpp_shr1_i(u.i[1]);
  return u.q;
}
__device__ __forceinline__ unsigned long long readlane_u64(unsigned long long x, int l){
  union { unsigned long long q; int i[2]; } u; u.q = x;
  union { unsigned long long q; int i[2]; } r;
  r.i[0] = __builtin_amdgcn_readlane(u.i[0], l);
  r.i[1] = __builtin_amdgcn_readlane(u.i[1], l);
  return r.q;
}
// sort key: d2 (clamped >=0) bits, low 13 mantissa bits replaced by idx.
__device__ __forceinline__ unsigned long long d2key(double d2, int idx){
  d2 = fmax(d2, 0.0);
  union { double d; unsigned long long q; } u; u.d = d2;
  return (u.q & ~0x1FFFull) | (unsigned long long)idx;
}
__device__ __forceinline__ double key_upper_d2(unsigned long long k){
  union { unsigned long long q; double d; } u; u.q = k | 0x1FFFull;   // round up: conservative
  return u.d;
}
__device__ __forceinline__ int cell1(float x){
  int c = (int)floorf((x - GLOF)*(1.0f/GHF));
  return min(max(c, 0), GR_-1);
}

// DPP float move (ctrl as template constant; all rows/banks, bound_ctrl=1)
template<int CTRL>
__device__ __forceinline__ float dppf(float x){
  union { float f; int i; } u; u.f = x;
  u.i = __builtin_amdgcn_update_dpp(0, u.i, CTRL, 0xF, 0xF, true);
  return u.f;
}
// 16-lane row sum, identical pairing to xor1/2/4/8 butterfly (bit-identical result)
__device__ __forceinline__ float red16(float x){
  x += dppf<0xB1>(x);    // quad_perm [1,0,3,2] : xor 1
  x += dppf<0x4E>(x);    // quad_perm [2,3,0,1] : xor 2
  x += dppf<0x141>(x);   // row_half_mirror     : xor 4
  x += dppf<0x140>(x);   // row_mirror          : xor 8
  return x;
}

// ---------------- pack xyz -> float4 (w=|p|^2 fp32) + feat -> bf16 PM + cell histogram ----------------
__global__ __launch_bounds__(256) void pack_featb_kernel(const float* __restrict__ xyz,
    const float* __restrict__ feat, float4* __restrict__ pt4, ushort* __restrict__ fb,
    int* __restrict__ cellCnt){
  int e = blockIdx.x*256 + threadIdx.x;
  int b = e >> 13, n = e & (N_-1);
  const float* xb = xyz + b*3*N_;
  float x = xb[n], y = xb[N_+n], z = xb[2*N_+n];
  pt4[e] = make_float4(x, y, z, x*x + y*y + z*z);
  atomicAdd(&cellCnt[b*NC_ + (cell1(z)*GR_ + cell1(y))*GR_ + cell1(x)], 1);
  const float* xin = feat + b*CN_ + n;
  #pragma unroll
  for (int c0 = 0; c0 < C_; c0 += 8){
    s16x8 o8;
    #pragma unroll
    for (int i = 0; i < 8; i++) o8[i] = f2b(xin[(size_t)(c0+i)*N_]);
    *(s16x8*)(fb + (size_t)e*C_ + c0) = o8;
  }
}

// ---------------- exclusive prefix scan over 2*NC_ = 27648 cells (single block, 27/thread) ----------------
__global__ __launch_bounds__(1024) void scan_kernel(const int* __restrict__ cnt,
    int* __restrict__ cellStart, int* __restrict__ cellCur){
  __shared__ int bs[1024];
  int t = threadIdx.x;
  int base = t*27;
  int s = 0;
  for (int i = 0; i < 27; i++) s += cnt[base+i];
  bs[t] = s;
  __syncthreads();
  for (int off = 1; off < 1024; off <<= 1){
    int v = (t >= off) ? bs[t-off] : 0;
    __syncthreads();
    bs[t] += v;
    __syncthreads();
  }
  int run = (t == 0) ? 0 : bs[t-1];
  for (int i = 0; i < 27; i++){
    cellStart[base+i] = run;
    cellCur[base+i]  = run;
    run += cnt[base+i];
  }
  if (t == 1023) cellStart[2*NC_] = BN_;
}

// ---------------- scatter points into cell-sorted order ----------------
__global__ __launch_bounds__(256) void scatter_kernel(const float4* __restrict__ pt4,
    int* __restrict__ cellCur, float4* __restrict__ spts, int* __restrict__ sidx){
  int e = blockIdx.x*256 + threadIdx.x;
  int b = e >> 13;
  float4 p = pt4[e];
  int cid = b*NC_ + (cell1(p.z)*GR_ + cell1(p.y))*GR_ + cell1(p.x);
  int slot = atomicAdd(&cellCur[cid], 1);
  spts[slot] = p;
  sidx[slot] = e & (N_-1);
}

// ---------------- KNN hybrid: ring-1 grid pass; 2x-unrolled brute fallback ----------------
__global__ __launch_bounds__(512) void knn_kernel(const float4* __restrict__ pt4,
    const float4* __restrict__ spts, const int* __restrict__ sidx,
    const int* __restrict__ cellStart, int* __restrict__ idxo){
  int lane = threadIdx.x & 63, wid = threadIdx.x >> 6;
  int qg = blockIdx.x*8 + wid;           // sorted slot
  int b = qg >> 13;
  float4 qp = spts[qg];
  int nq = sidx[qg];                     // original point index within batch
  double qx = qp.x, qy = qp.y, qz = qp.z;
  double qsq = qx*qx + qy*qy + qz*qz;
  float qx2 = -2.f*qp.x, qy2 = -2.f*qp.y, qz2 = -2.f*qp.z;
  unsigned long long mykey = EMPTY_KEY;  // lanes 0..15: sorted top-16 keys
  float cmpv = FLT_MAX;
  int ci = cell1(qp.x), cj = cell1(qp.y), ck = cell1(qp.z);

  auto process = [&](unsigned long long m, unsigned long long keyv){
    while (m){
      int src = __ffsll(m) - 1; m &= m - 1;
      unsigned long long kn = readlane_u64(keyv, src);
      bool less = kn < mykey;
      unsigned long long bm = __ballot(less) & 0xFFFFull;
      if (bm){
        int pos = __ffsll(bm) - 1;
        unsigned long long pk = dpp_shr1_u64(mykey);
        if (lane < 16){
          if (lane > pos) mykey = pk;
          else if (lane == pos) mykey = kn;
        }
      }
    }
  };

  auto do_range = [&](int cid0, int cid1){
    int s = cellStart[cid0], e = cellStart[cid1+1];
    for (int off = s; off < e; off += 64){
      int t = off + lane;
      bool valid = t < e;
      float4 pp = make_float4(0.f, 0.f, 0.f, 3.0e38f);
      int oi = 0;
      if (valid){ pp = spts[t]; oi = sidx[t]; }
      float f = fmaf(pp.x, qx2, fmaf(pp.y, qy2, fmaf(pp.z, qz2, pp.w)));
      unsigned long long m = __ballot(valid && (f < cmpv));
      if (m){
        double px = pp.x, py = pp.y, pz = pp.z;
        double psq = px*px + py*py + pz*pz;
        double dot = qx*px + qy*py + qz*pz;
        process(m, d2key(qsq + psq - 2.0*dot, oi));
        cmpv = fminf(cmpv, (float)(key_upper_d2(readlane_u64(mykey, 15)) - qsq) + KNN_MARGIN);
      }
    }
  };

  // phase 1: ring 0+1 as 9 contiguous x-runs; own row first for fast threshold convergence
  int x0 = max(ci-1, 0), x1 = min(ci+1, GR_-1);
  int cbase = b*NC_;
  do_range(cbase + (ck*GR_ + cj)*GR_ + x0, cbase + (ck*GR_ + cj)*GR_ + x1);
  for (int dz = -1; dz <= 1; dz++){
    int z = ck + dz; if (z < 0 || z >= GR_) continue;
    for (int dy = -1; dy <= 1; dy++){
      int y = cj + dy; if (y < 0 || y >= GR_) continue;
      if ((dy | dz) == 0) continue;
      do_range(cbase + (z*GR_ + y)*GR_ + x0, cbase + (z*GR_ + y)*GR_ + x1);
    }
  }

  // exact coverage bound: points outside ring-1 are >= h away (cells exact in fp32)
  double thr_up = key_upper_d2(readlane_u64(mykey, 15));
  if (thr_up > (double)GHF*(double)GHF){
    // phase 2: brute-force over original order (2x unrolled); reset list, keep filter
    mykey = EMPTY_KEY;
    const float4* pts = pt4 + (b << 13);
    for (int t0 = 0; t0 < N_; t0 += 128){
      float4 pA = pts[t0 + lane];
      float4 pB = pts[t0 + 64 + lane];
      float fA = fmaf(pA.x, qx2, fmaf(pA.y, qy2, fmaf(pA.z, qz2, pA.w)));
      float fB = fmaf(pB.x, qx2, fmaf(pB.y, qy2, fmaf(pB.z, qz2, pB.w)));
      unsigned long long mA = __ballot(fA < cmpv);
      unsigned long long mB = __ballot(fB < cmpv);
      if (mA | mB){
        if (mA){
          double px = pA.x, py = pA.y, pz = pA.z;
          double psq = px*px + py*py + pz*pz;
          double dot = qx*px + qy*py + qz*pz;
          process(mA, d2key(qsq + psq - 2.0*dot, t0 + lane));
        }
        if (mB){
          double px = pB.x, py = pB.y, pz = pB.z;
          double psq = px*px + py*py + pz*pz;
          double dot = qx*px + qy*py + qz*pz;
          process(mB, d2key(qsq + psq - 2.0*dot, t0 + 64 + lane));
        }
        cmpv = fminf(cmpv, (float)(key_upper_d2(readlane_u64(mykey, 15)) - qsq) + KNN_MARGIN);
      }
    }
  }
  if (lane < 16) idxo[((size_t)(b<<13) + nq)*K_ + lane] = (int)(mykey & 0x1FFFull);
}

// ---------------- setup: fused weights (3 x 128^3) + fused biases ----------------
__global__ __launch_bounds__(256) void setup_kernel(const float* __restrict__ W_att1,
    const float* __restrict__ W_pos2, const float* __restrict__ W_q, const float* __restrict__ W_k,
    const float* __restrict__ b_pos2, const float* __restrict__ b_att1,
    const float* __restrict__ b_q, const float* __restrict__ b_k,
    float* __restrict__ Wf, float* __restrict__ Wqa, float* __restrict__ Wka,
    float* __restrict__ bG1, float* __restrict__ bqa, float* __restrict__ bka){
  int bx = blockIdx.x;
  if (bx < 192){
    int which = bx >> 6;
    const float* Bm = which==0 ? W_pos2 : (which==1 ? W_q : W_k);
    float* Cm = which==0 ? Wf : (which==1 ? Wqa : Wka);
    int e = (bx & 63)*256 + threadIdx.x;
    int o = e >> 7, c = e & 127;
    float s = 0.f;
    #pragma unroll 8
    for (int m = 0; m < 128; m++) s += W_att1[o*128+m]*Bm[m*128+c];
    Cm[e] = s;
  } else {
    for (int t = threadIdx.x; t < 384; t += 256){
      int which = t >> 7, o = t & 127;
      const float* v = which==0 ? b_pos2 : (which==1 ? b_q : b_k);
      float* out = which==0 ? bG1 : (which==1 ? bqa : bka);
      float s = which==0 ? b_att1[o] : 0.f;
      for (int m = 0; m < 128; m++) s += W_att1[o*128+m]*v[m];
      out[o] = s;
    }
  }
}

// ---------------- pos moments: per-batch [R(3), S_diag(3), S_off(3)] over rel = pj - pn ----------------
__global__ __launch_bounds__(256) void posmom_kernel(const float4* __restrict__ pt4,
    const int* __restrict__ idx, float* __restrict__ mom){
  __shared__ float ls[9];
  if (threadIdx.x < 9) ls[threadIdx.x] = 0.f;
  __syncthreads();
  int p = blockIdx.x*256 + threadIdx.x;
  int b = p >> 17;
  int n = p >> 4;
  int j = idx[p];
  float4 pj = pt4[(b<<13) + j], pn = pt4[n];
  float rx = pj.x - pn.x, ry = pj.y - pn.y, rz = pj.z - pn.z;
  float m9[9] = { rx, ry, rz, rx*rx, ry*ry, rz*rz, rx*ry, rx*rz, ry*rz };
  #pragma unroll
  for (int i = 0; i < 9; i++){
    float s = m9[i];
    #pragma unroll
    for (int mk = 32; mk; mk >>= 1) s += __shfl_xor(s, mk, 64);
    if ((threadIdx.x & 63) == 0) atomicAdd(&ls[i], s);
  }
  __syncthreads();
  if (threadIdx.x < 9) atomicAdd(&mom[b*9 + threadIdx.x], ls[threadIdx.x]);
}

// ---------------- pos finalize from moments + folded GN params (float4: sx,sy,sz,so) ----------------
__global__ void posfin_kernel(const float* __restrict__ mom,
    const float* __restrict__ W1, const float* __restrict__ b1,
    const float* __restrict__ g1, const float* __restrict__ be1, float* __restrict__ prm){
  int i = threadIdx.x;           // 256: b = i>>7, c = i&127
  int b = i >> 7, c = i & 127;
  const float* M = mom + b*9;
  float wx = W1[3*c], wy = W1[3*c+1], wz = W1[3*c+2], bb = b1[c];
  const float cnt = (float)NK_;
  float wr = wx*M[0] + wy*M[1] + wz*M[2];
  float s_c = wr + bb*cnt;
  float q_c = wx*wx*M[3] + wy*wy*M[4] + wz*wz*M[5]
            + 2.f*(wx*wy*M[6] + wx*wz*M[7] + wy*wz*M[8])
            + 2.f*bb*wr + bb*bb*cnt;
  #pragma unroll
  for (int mk = 1; mk < 16; mk <<= 1){
    s_c += __shfl_xor(s_c, mk, 64);
    q_c += __shfl_xor(q_c, mk, 64);
  }
  const float invcnt = 1.0f/(16.0f*(float)NK_);
  float m = s_c*invcnt;
  float var = q_c*invcnt - m*m;
  var = fmaxf(var, 0.f);
  float r = rsqrtf(var + EPSV);
  float rs = r*g1[c];
  float4* p4 = (float4*)prm;
  p4[b*128 + c] = make_float4(wx*rs, wy*rs, wz*rs, (bb-m)*rs + be1[c]);
}

// ---------------- att finalize + folded scale/shift (interleaved float2: sc,sh) ----------------
__global__ void attfin_kernel(const float* __restrict__ gsum, const float* __restrict__ gssq,
    const float* __restrict__ ga, const float* __restrict__ bea, float* __restrict__ prm, float invcnt){
  __shared__ float sm[16], sr[16];
  int i = threadIdx.x;
  if (i < 16){
    float m = gsum[i]*invcnt;
    float v = gssq[i]*invcnt - m*m;
    v = fmaxf(v, 0.f);
    sm[i] = m; sr[i] = rsqrtf(v + EPSV);
  }
  __syncthreads();
  int b = i >> 7, c = i & 127, g = c >> 4;
  float sc = ga[c]*sr[b*G_+g];
  float2* p2 = (float2*)prm;
  p2[b*128 + c] = make_float2(sc, bea[c] - sm[b*G_+g]*sc);
}

// ---------------- unified MFMA GEMM body: Y[o][p] = W*X + bias, 64 pts x 128 out ----------------
#define ST_COPY 0
#define ST_GN   1
#define ST_POS  2
#define EP_PM    0
#define EP_QKS   1
#define EP_F32CM 2

template<int STAGE>
__device__ __forceinline__ void stage_x(ushort* xs,
    const ushort* __restrict__ Xb, const float* __restrict__ prm,
    const float4* __restrict__ pt4, const int* __restrict__ idx, int p0, int b)
{
  int tid = threadIdx.x;
  int row = tid & 63, cc = tid >> 6;
  if constexpr (STAGE == ST_COPY){
    const ushort* src = Xb + (size_t)(p0+row)*C_ + cc*32;
    #pragma unroll
    for (int q = 0; q < 4; q++){
      s16x8 v8 = *(const s16x8*)(src + q*8);
      int sl = (cc*4+q) ^ (row&7);
      *(s16x8*)(xs + row*C_ + sl*8) = v8;
    }
  } else if constexpr (STAGE == ST_GN){
    const ushort* src = Xb + (size_t)(p0+row)*C_ + cc*32;
    const float2* pr = (const float2*)prm + b*128;
    #pragma unroll
    for (int q = 0; q < 4; q++){
      s16x8 v8 = *(const s16x8*)(src + q*8);
      s16x8 o8;
      #pragma unroll
      for (int i = 0; i < 8; i++){
        int c = cc*32 + q*8 + i;
        float2 s2 = pr[c];
        o8[i] = f2b(leakyf(b2f(v8[i])*s2.x + s2.y));
      }
      int sl = (cc*4+q) ^ (row&7);
      *(s16x8*)(xs + row*C_ + sl*8) = o8;
    }
  } else { // ST_POS
    int p = p0 + row;
    int ng = p >> 4;
    int j = idx[p];
    float4 pj = pt4[(b<<13) + j], pn = pt4[ng];
    float rx = pj.x - pn.x, ry = pj.y - pn.y, rz = pj.z - pn.z;
    const float4* pr = (const float4*)prm + b*128;
    #pragma unroll
    for (int q = 0; q < 4; q++){
      s16x8 o8;
      #pragma unroll
      for (int i = 0; i < 8; i++){
        int c = cc*32 + q*8 + i;
        float4 s4 = pr[c];
        o8[i] = f2b(leakyf(fmaf(s4.x, rx, fmaf(s4.y, ry, fmaf(s4.z, rz, s4.w)))));
      }
      int sl = (cc*4+q) ^ (row&7);
      *(s16x8*)(xs + row*C_ + sl*8) = o8;
    }
  }
}

__device__ __forceinline__ void load_afr(s16x8 afr[2][4], const float* __restrict__ W, int wid, int lm, int lh){
  #pragma unroll
  for (int t = 0; t < 2; t++){
    int T = wid*2 + t;
    #pragma unroll
    for (int ks = 0; ks < 4; ks++){
      const float* wr = W + (size_t)(T*16 + lm)*C_ + ks*32 + lh*8;
      float4 w0 = *(const float4*)wr;
      float4 w1 = *(const float4*)(wr+4);
      s16x8 a;
      a[0]=f2b(w0.x); a[1]=f2b(w0.y); a[2]=f2b(w0.z); a[3]=f2b(w0.w);
      a[4]=f2b(w1.x); a[5]=f2b(w1.y); a[6]=f2b(w1.z); a[7]=f2b(w1.w);
      afr[t][ks] = a;
    }
  }
}

__device__ __forceinline__ void mfma_tile(f32x4 acc[2][4], const s16x8 afr[2][4],
    const ushort* xs, const float* __restrict__ bias, int wid, int lm, int lh)
{
  #pragma unroll
  for (int t = 0; t < 2; t++){
    f32x4 bs = *(const f32x4*)(bias + (wid*2+t)*16 + lh*4);
    #pragma unroll
    for (int ps = 0; ps < 4; ps++) acc[t][ps] = bs;
  }
  #pragma unroll
  for (int ps = 0; ps < 4; ps++){
    int row = ps*16 + lm;
    s16x8 bf[4];
    #pragma unroll
    for (int ks = 0; ks < 4; ks++){
      int sl = (ks*4+lh) ^ (row&7);
      bf[ks] = *(const s16x8*)(xs + row*C_ + sl*8);
    }
    #pragma unroll
    for (int ks = 0; ks < 4; ks++){
      #pragma unroll
      for (int t = 0; t < 2; t++)
        acc[t][ps] = __builtin_amdgcn_mfma_f32_16x16x32_bf16(afr[t][ks], bf[ks], acc[t][ps], 0,0,0);
    }
  }
}

template<int STAGE, int EPI>
__device__ __forceinline__ void mgemm_body(ushort* xs, float* sblk,
    const ushort* __restrict__ Xb, const float* __restrict__ W, const float* __restrict__ bias,
    const float* __restrict__ prm, const float4* __restrict__ pt4, const int* __restrict__ idx,
    const ushort* __restrict__ Aq, const ushort* __restrict__ Ak,
    void* __restrict__ Y, float* __restrict__ gsum, float* __restrict__ gssq, int bsh, int bx)
{
  int tid = threadIdx.x;
  int l = tid & 63, wid = tid >> 6;
  int lm = l & 15, lh = l >> 4;
  int p0 = bx * 64;
  int b = p0 >> bsh;

  if (tid < 16) sblk[tid] = 0.f;

  s16x8 afr[2][4];
  load_afr(afr, W, wid, lm, lh);
  stage_x<STAGE>(xs, Xb, prm, pt4, idx, p0, b);
  __syncthreads();

  f32x4 acc[2][4];
  mfma_tile(acc, afr, xs, bias, wid, lm, lh);

  // ---- epilogue ----
  float gs[2] = {0.f,0.f}, gq[2] = {0.f,0.f};
  #pragma unroll
  for (int t = 0; t < 2; t++){
    int T = wid*2 + t;
    int o0 = T*16 + lh*4;
    #pragma unroll
    for (int ps = 0; ps < 4; ps++){
      int p = p0 + ps*16 + lm;
      if constexpr (EPI == EP_PM){
        s16x4 r4;
        #pragma unroll
        for (int r = 0; r < 4; r++) r4[r] = f2b(acc[t][ps][r]);
        *(s16x4*)((ushort*)Y + (size_t)p*C_ + o0) = r4;
      } else if constexpr (EPI == EP_QKS){
        int ng = p >> 4;
        int j = idx[p];
        s16x4 aq4 = *(const s16x4*)(Aq + (size_t)ng*C_ + o0);
        s16x4 ak4 = *(const s16x4*)(Ak + ((size_t)(b<<13)+j)*C_ + o0);
        s16x4 r4;
        #pragma unroll
        for (int r = 0; r < 4; r++){
          float v = acc[t][ps][r] + b2f(aq4[r]) - b2f(ak4[r]);
          r4[r] = f2b(v);
          gs[t] += v; gq[t] += v*v;
        }
        *(s16x4*)((ushort*)Y + (size_t)p*C_ + o0) = r4;
      } else { // EP_F32CM
        float* yf = (float*)Y;
        #pragma unroll
        for (int r = 0; r < 4; r++){
          float v = acc[t][ps][r];
          yf[(size_t)(o0+r)*BN_ + p] = v;
          gs[t] += v; gq[t] += v*v;
        }
      }
    }
  }

  if constexpr (EPI == EP_QKS || EPI == EP_F32CM){
    #pragma unroll
    for (int t = 0; t < 2; t++){
      float s = gs[t], q = gq[t];
      #pragma unroll
      for (int mk = 32; mk; mk >>= 1){ s += __shfl_xor(s, mk, 64); q += __shfl_xor(q, mk, 64); }
      if (l == 0){
        int T = wid*2 + t;
        atomicAdd(&sblk[T], s); atomicAdd(&sblk[8+T], q);
      }
    }
    __syncthreads();
    if (tid < 8){
      atomicAdd(&gsum[b*G_ + tid], sblk[tid]);
      atomicAdd(&gssq[b*G_ + tid], sblk[8+tid]);
    }
  }
}

template<int STAGE, int EPI>
__global__ __launch_bounds__(256) void mgemm_kernel(
    const ushort* __restrict__ Xb, const float* __restrict__ W, const float* __restrict__ bias,
    const float* __restrict__ prm, const float4* __restrict__ pt4, const int* __restrict__ idx,
    const ushort* __restrict__ Aq, const ushort* __restrict__ Ak,
    void* __restrict__ Y, float* __restrict__ gsum, float* __restrict__ gssq, int bsh)
{
  __shared__ ushort xs[64*128];
  __shared__ float sblk[16];
  mgemm_body<STAGE,EPI>(xs, sblk, Xb, W, bias, prm, pt4, idx, Aq, Ak, Y, gsum, gssq, bsh, blockIdx.x);
}

// v / Aq / Ak in one launch (gridDim.y = 3)
__global__ __launch_bounds__(256) void qkv_kernel(const ushort* __restrict__ nfb,
    const float* __restrict__ Wv, const float* __restrict__ bv,
    const float* __restrict__ Wqa, const float* __restrict__ bqa,
    const float* __restrict__ Wka, const float* __restrict__ bka,
    ushort* __restrict__ vb, ushort* __restrict__ Aqb, ushort* __restrict__ Akb)
{
  __shared__ ushort xs[64*128];
  __shared__ float sblk[16];
  if (blockIdx.y == 0)
    mgemm_body<ST_COPY,EP_PM>(xs, sblk, nfb, Wv, bv, nullptr, nullptr, nullptr, nullptr, nullptr, vb, nullptr, nullptr, 13, blockIdx.x);
  else if (blockIdx.y == 1)
    mgemm_body<ST_COPY,EP_PM>(xs, sblk, nfb, Wqa, bqa, nullptr, nullptr, nullptr, nullptr, nullptr, Aqb, nullptr, nullptr, 13, blockIdx.x);
  else
    mgemm_body<ST_COPY,EP_PM>(xs, sblk, nfb, Wka, bka, nullptr, nullptr, nullptr, nullptr, nullptr, Akb, nullptr, nullptr, 13, blockIdx.x);
}

// ---------------- fused: GN(att1) -> W_att2 GEMM -> softmax(k) -> PV + residual ----------------
// Single 64-pt tile per block (R15-proven config): early V prefetch + DPP reductions.
__global__ __launch_bounds__(256) void fatt_kernel(const ushort* __restrict__ Xb /*att1 PM*/,
    const float* __restrict__ W /*W_att2*/, const float* __restrict__ bias /*b_att2*/,
    const float* __restrict__ prm /*attPrm*/, const int* __restrict__ idx,
    const ushort* __restrict__ vb, const ushort* __restrict__ nfb, ushort* __restrict__ outb)
{
  __shared__ ushort xs[64*C_];
  int tid = threadIdx.x;
  int l = tid & 63, wid = tid >> 6;
  int lm = l & 15, lh = l >> 4;
  int p0 = blockIdx.x * 64;
  int b = p0 >> 17;

  // prefetch V gathers first (latency overlaps staging global loads + transform + MFMA)
  s16x4 vpre[2][4];
  #pragma unroll
  for (int ps = 0; ps < 4; ps++){
    int p = p0 + ps*16 + lm;
    int j = idx[p];
    const ushort* vr = vb + ((size_t)(b<<13)+j)*C_ + lh*4;
    #pragma unroll
    for (int t = 0; t < 2; t++)
      vpre[t][ps] = *(const s16x4*)(vr + (wid*2+t)*16);
  }

  s16x8 afr[2][4];
  load_afr(afr, W, wid, lm, lh);
  stage_x<ST_GN>(xs, Xb, prm, nullptr, nullptr, p0, b);
  __syncthreads();

  f32x4 acc[2][4];
  mfma_tile(acc, afr, xs, bias, wid, lm, lh);

  // softmax over k (lm) + PV + residual — DPP row reductions (VALU-only)
  #pragma unroll
  for (int t = 0; t < 2; t++){
    int o0 = (wid*2+t)*16 + lh*4;
    #pragma unroll
    for (int ps = 0; ps < 4; ps++){
      s16x4 v4 = vpre[t][ps];
      f32x4 e, pv;
      #pragma unroll
      for (int r = 0; r < 4; r++){
        float ev = __expf(acc[t][ps][r]);
        e[r] = ev;
        pv[r] = ev * b2f(v4[r]);
      }
      #pragma unroll
      for (int r = 0; r < 4; r++){
        e[r]  = red16(e[r]);
        pv[r] = red16(pv[r]);
      }
      if (lm == 0){
        int n = (p0 + ps*16) >> 4;
        s16x4 n4 = *(const s16x4*)(nfb + (size_t)n*C_ + o0);
        s16x4 o4;
        #pragma unroll
        for (int r = 0; r < 4; r++) o4[r] = f2b(pv[r]/e[r] + b2f(n4[r]));
        *(s16x4*)(outb + (size_t)n*C_ + o0) = o4;
      }
    }
  }
}

// ---------------- final: inline post-finalize + GN + leaky (out1 col-major [C][BN]) ----------------
__global__ __launch_bounds__(256) void final_kernel(const float* __restrict__ out1,
    const float* __restrict__ gsum, const float* __restrict__ gssq,
    const float* __restrict__ g, const float* __restrict__ be, float* __restrict__ out){
  int e = blockIdx.x*256 + threadIdx.x;
  int b = e >> 20;
  int c = (e >> 13) & (C_-1);
  int n = e & (N_-1);
  int gi = b*G_ + (c >> 4);
  const float invcnt = 1.0f/(float)(16*N_);
  float m = gsum[gi]*invcnt;
  float var = gssq[gi]*invcnt - m*m;
  var = fmaxf(var, 0.f);
  float r = rsqrtf(var + EPSV);
  float v = (out1[(size_t)c*BN_ + b*N_ + n] - m) * r;
  v = v*g[c] + be[c];
  out[e] = leakyf(v);
}

extern "C" void kernel_launch(void* const* d_in, const int* in_sizes, int n_in,
                              void* d_out, int out_size, void* d_ws, size_t ws_size,
                              hipStream_t stream) {
  const float* xyz    = (const float*)d_in[0];
  const float* feat   = (const float*)d_in[1];
  const float* W_pre  = (const float*)d_in[2];
  const float* b_pre  = (const float*)d_in[3];
  const float* W_pos1 = (const float*)d_in[4];
  const float* b_pos1 = (const float*)d_in[5];
  const float* g_pos1 = (const float*)d_in[6];
  const float* be_pos1= (const float*)d_in[7];
  const float* W_pos2 = (const float*)d_in[8];
  const float* b_pos2 = (const float*)d_in[9];
  const float* W_q    = (const float*)d_in[10];
  const float* b_q    = (const float*)d_in[11];
  const float* W_k    = (const float*)d_in[12];
  const float* b_k    = (const float*)d_in[13];
  const float* W_v    = (const float*)d_in[14];
  const float* b_v    = (const float*)d_in[15];
  const float* W_att1 = (const float*)d_in[16];
  const float* b_att1 = (const float*)d_in[17];
  const float* g_att1 = (const float*)d_in[18];
  const float* be_att1= (const float*)d_in[19];
  const float* W_att2 = (const float*)d_in[20];
  const float* b_att2 = (const float*)d_in[21];
  const float* W_post = (const float*)d_in[22];
  const float* b_post = (const float*)d_in[23];
  const float* g_post = (const float*)d_in[24];
  const float* be_post= (const float*)d_in[25];

  char* w = (char*)d_ws;
  float4* pt4 = (float4*)w;            w += sizeof(float4)*BN_;
  int* idx = (int*)w;                  w += sizeof(int)*BNK_;
  ushort* fb   = (ushort*)w;           w += (size_t)2*BN_*C_;
  ushort* nfb  = (ushort*)w;           w += (size_t)2*BN_*C_;
  ushort* vb   = (ushort*)w;           w += (size_t)2*BN_*C_;
  ushort* Aqb  = (ushort*)w;           w += (size_t)2*BN_*C_;
  ushort* Akb  = (ushort*)w;           w += (size_t)2*BN_*C_;
  ushort* outb = (ushort*)w;           w += (size_t)2*BN_*C_;
  float* out1  = (float*)w;            w += (size_t)4*BN_*C_;
  ushort* bufA = (ushort*)w;           w += (size_t)2*BNK_*C_;           // att1 PM
  float* Wf    = (float*)w;            w += sizeof(float)*C_*C_;
  float* Wqa   = (float*)w;            w += sizeof(float)*C_*C_;
  float* Wka   = (float*)w;            w += sizeof(float)*C_*C_;
  float* bG1   = (float*)w;            w += 512;
  float* bqa   = (float*)w;            w += 512;
  float* bka   = (float*)w;            w += 512;
  float* posPrm= (float*)w;            w += sizeof(float)*1024;
  float* attPrm= (float*)w;            w += sizeof(float)*512;
  float* stats = (float*)w;            w += 1024;
  int* cellCnt = (int*)w;              w += sizeof(int)*2*NC_;
  int* cellStart=(int*)w;              w += sizeof(int)*(2*NC_+1);
  int* cellCur = (int*)w;              w += sizeof(int)*2*NC_;
  float4* spts = (float4*)w;           w += sizeof(float4)*BN_;
  int* sidx    = (int*)w;              w += sizeof(int)*BN_;

  float* posMom = stats + 0;                     // 2*9 floats
  float* att_sum = stats + 64, *att_ssq = stats + 80;
  float* post_sum= stats +128, *post_ssq= stats +144;

  hipMemsetAsync(stats, 0, 1024, stream);
  hipMemsetAsync(cellCnt, 0, sizeof(int)*2*NC_, stream);

  pack_featb_kernel<<<BN_/256, 256, 0, stream>>>(xyz, feat, pt4, fb, cellCnt);
  scan_kernel<<<1, 1024, 0, stream>>>(cellCnt, cellStart, cellCur);
  scatter_kernel<<<BN_/256, 256, 0, stream>>>(pt4, cellCur, spts, sidx);
  knn_kernel<<<BN_/8, 512, 0, stream>>>(pt4, spts, sidx, cellStart, idx);

  // fused weights / biases (one launch)
  setup_kernel<<<193, 256, 0, stream>>>(W_att1, W_pos2, W_q, W_k, b_pos2, b_att1, b_q, b_k,
      Wf, Wqa, Wka, bG1, bqa, bka);

  // nf = W_pre*feat + b
  mgemm_kernel<ST_COPY,EP_PM><<<BN_/64, 256, 0, stream>>>(fb, W_pre, b_pre, nullptr, nullptr, nullptr,
      nullptr, nullptr, nfb, nullptr, nullptr, 13);
  // v, Aq, Ak (one launch)
  qkv_kernel<<<dim3(BN_/64, 3), 256, 0, stream>>>(nfb, W_v, b_v, Wqa, bqa, Wka, bka, vb, Aqb, Akb);

  // pos GN stats via moments -> folded params
  posmom_kernel<<<BNK_/256, 256, 0, stream>>>(pt4, idx, posMom);
  posfin_kernel<<<1, 256, 0, stream>>>(posMom, W_pos1, b_pos1, g_pos1, be_pos1, posPrm);

  // G1: att1 = Wf*posn + bG1 + Aq[n] - Ak[j]  (+ stats)  -> bufA
  mgemm_kernel<ST_POS,EP_QKS><<<BNK_/64, 256, 0, stream>>>(nullptr, Wf, bG1, posPrm, pt4, idx,
      Aqb, Akb, bufA, att_sum, att_ssq, 17);
  attfin_kernel<<<1, 256, 0, stream>>>(att_sum, att_ssq, g_att1, be_att1, attPrm, 1.0f/(float)(16.0*NK_));

  // fused G2 + softmax + PV + residual (single tile per block, R15 config)
  fatt_kernel<<<BNK_/64, 256, 0, stream>>>(bufA, W_att2, b_att2, attPrm, idx, vb, nfb, outb);

  // post conv + stats (f32 col-major)
  mgemm_kernel<ST_COPY,EP_F32CM><<<BN_/64, 256, 0, stream>>>(outb, W_post, b_post, nullptr, nullptr, nullptr,
      nullptr, nullptr, out1, post_sum, post_ssq, 13);
  final_kernel<<<(B_*CN_)/256, 256, 0, stream>>>(out1, post_sum, post_ssq, g_post, be_post, (float*)d_out);
}